// Round 5
// baseline (11335.048 us; speedup 1.0000x reference)
//
#include <hip/hip_runtime.h>
#include <hip/hip_bf16.h>

typedef const float* fp;

// ---------- sentinel fill (diagnostic channel via absmax) ----------
__global__ __launch_bounds__(256) void k_fill(float* out, int n, float v){
  int i = blockIdx.x*256 + threadIdx.x;
  if(i < n) out[i] = v;
}

// ---------- input transpose: x [6,64,768] f32 -> h0 [6,768,64] f32 ----------
__global__ __launch_bounds__(256) void k_in_tr(fp x, float* h0){
  int n = blockIdx.x;           // 0..63
  int b = blockIdx.y;           // 0..5
  for(int d = threadIdx.x; d < 768; d += blockDim.x)
    h0[((size_t)b*768 + d)*64 + n] = x[((size_t)b*64 + n)*768 + d];
}

// ---------- direct 3x3 SAME conv, weights staged in LDS ----------
__global__ __launch_bounds__(256) void k_conv3(const float* __restrict__ in, fp w, fp bias,
                                               float* __restrict__ out,
                                               int Cin, int Cout, int H, int W){
  int bc = blockIdx.x; int b = bc / Cout; int co = bc % Cout;
  extern __shared__ float ws[];            // Cin*9 floats
  int nw = Cin*9;
  for(int i = threadIdx.x; i < nw; i += blockDim.x) ws[i] = w[(size_t)co*nw + i];
  __syncthreads();
  int N = H*W;
  const float* inb = in + (size_t)b*Cin*N;
  float bv = bias ? bias[co] : 0.f;
  for(int p = threadIdx.x; p < N; p += blockDim.x){
    int y = p / W, x = p % W;
    float acc = bv;
    for(int ci = 0; ci < Cin; ci++){
      const float* ip = inb + (size_t)ci*N;
      const float* wp = ws + ci*9;
      for(int ky = 0; ky < 3; ky++){
        int yy = y + ky - 1; if((unsigned)yy >= (unsigned)H) continue;
        const float* row = ip + yy*W;
        for(int kx = 0; kx < 3; kx++){
          int xx = x + kx - 1; if((unsigned)xx >= (unsigned)W) continue;
          acc += row[xx] * wp[ky*3+kx];
        }
      }
    }
    out[((size_t)b*Cout + co)*N + p] = acc;
  }
}

// ---------- fused up2 + 1x1 conv (+bias) ----------
__global__ __launch_bounds__(256) void k_up_conv1(const float* __restrict__ in, fp w, fp bias,
                                                  float* __restrict__ out,
                                                  int Cin, int Cout, int H2, int W2){
  int bc = blockIdx.x; int b = bc / Cout; int co = bc % Cout;
  extern __shared__ float ws[];            // Cin floats
  for(int i = threadIdx.x; i < Cin; i += blockDim.x) ws[i] = w[(size_t)co*Cin + i];
  __syncthreads();
  int N2 = H2*W2, W1 = W2/2, N1 = (H2/2)*W1;
  const float* inb = in + (size_t)b*Cin*N1;
  float bv = bias[co];
  for(int p = threadIdx.x; p < N2; p += blockDim.x){
    int y = p / W2, x = p % W2;
    int q = (y>>1)*W1 + (x>>1);
    float acc = bv;
    for(int ci = 0; ci < Cin; ci++) acc += inb[(size_t)ci*N1 + q] * ws[ci];
    out[((size_t)b*Cout + co)*N2 + p] = acc;
  }
}

// ---------- concat channels: [a ; skip] -> cat f32 ----------
__global__ __launch_bounds__(256) void k_concat(const float* __restrict__ a, fp skip,
                                                float* __restrict__ cat, int Ca, int Cs, int N){
  int bc = blockIdx.x; int C = Ca + Cs; int b = bc / C; int c = bc % C;
  float* o = cat + (size_t)bc*N;
  if(c < Ca){
    const float* s = a + ((size_t)b*Ca + c)*N;
    for(int n = threadIdx.x; n < N; n += blockDim.x) o[n] = s[n];
  }else{
    fp s = skip + ((size_t)b*Cs + (c-Ca))*N;
    for(int n = threadIdx.x; n < N; n += blockDim.x) o[n] = s[n];
  }
}

// ---------- tiled transpose [6][C][N] -> [6][N][C] ----------
__global__ __launch_bounds__(256) void k_tr(const float* __restrict__ src, float* __restrict__ dst,
                                            int C, int N){
  __shared__ float t[32][33];
  int b = blockIdx.z;
  int c0 = blockIdx.y*32, n0 = blockIdx.x*32;
  int tx = threadIdx.x & 31, ty = threadIdx.x >> 5;   // 8 rows
  for(int i = ty; i < 32; i += 8) t[i][tx] = src[((size_t)b*C + c0+i)*N + n0+tx];
  __syncthreads();
  for(int i = ty; i < 32; i += 8) dst[((size_t)b*N + n0+i)*C + c0+tx] = t[tx][i];
}

// ---------- QKV projection: xt [6][N][C] @ {wq,wk,wv} -> Q,K,V [6][N][C] ----------
__global__ __launch_bounds__(256) void k_proj(const float* __restrict__ xt, fp wq, fp wk, fp wv,
                                              float* __restrict__ Q, float* __restrict__ K,
                                              float* __restrict__ V, int C, int N){
  int b = blockIdx.y, n = blockIdx.x;
  extern __shared__ float xs[];            // C floats
  const float* xp = xt + ((size_t)b*N + n)*C;
  for(int c = threadIdx.x; c < C; c += blockDim.x) xs[c] = xp[c];
  __syncthreads();
  for(int c = threadIdx.x; c < C; c += blockDim.x){
    float aq = 0.f, ak = 0.f, av = 0.f;
    for(int cc = 0; cc < C; cc++){
      float xv = xs[cc];
      aq += xv * wq[(size_t)cc*C + c];
      ak += xv * wk[(size_t)cc*C + c];
      av += xv * wv[(size_t)cc*C + c];
    }
    size_t o = ((size_t)b*N + n)*C + c;
    Q[o] = aq; K[o] = ak; V[o] = av;
  }
}

// ---------- flash core for one neighbor j: ctxn (+)= 0.5 * softmax(QK^T)V ----------
template<int C,int TQ,int TM>
__global__ __launch_bounds__(256) void k_attn_core(const float* __restrict__ Q,
                                                   const float* __restrict__ K,
                                                   const float* __restrict__ V,
                                                   float* __restrict__ ctxn, int N, int j){
  constexpr int CP = C + 1;
  __shared__ float qs[TQ][CP], ks[TM][CP], vs[TM][CP], os[TQ][CP];
  __shared__ float ss[TQ][TM];
  __shared__ float mrow[TQ], lrow[TQ], srow[TQ];
  int p = blockIdx.y, q0 = blockIdx.x*TQ, t = threadIdx.x;
  const float rs = rsqrtf((float)C);
  const float* Kb = K + (size_t)(p + (j ? 2 : 0))*N*C;
  const float* Vb = V + (size_t)(p + (j ? 2 : 0))*N*C;
  for(int i = t; i < TQ*C; i += 256){ int r = i/C, c = i%C;
    qs[r][c] = Q[((size_t)(p+1)*N + q0+r)*C + c] * rs; os[r][c] = 0.f; }
  if(t < TQ){ mrow[t] = -1e30f; lrow[t] = 0.f; }
  __syncthreads();
  for(int m0 = 0; m0 < N; m0 += TM){
    for(int i = t; i < TM*C; i += 256){ int m = i/C, c = i%C;
      ks[m][c] = Kb[(size_t)(m0+m)*C + c]; vs[m][c] = Vb[(size_t)(m0+m)*C + c]; }
    __syncthreads();
    for(int pr = t; pr < TQ*TM; pr += 256){
      int r = pr/TM, m = pr%TM;
      float a = 0.f;
      for(int c = 0; c < C; c++) a += qs[r][c]*ks[m][c];
      ss[r][m] = a;
    }
    __syncthreads();
    if(t < TQ){
      float mx = mrow[t];
      for(int m = 0; m < TM; m++) mx = fmaxf(mx, ss[t][m]);
      float scl = expf(mrow[t] - mx);
      float ps = 0.f;
      for(int m = 0; m < TM; m++){ float e = expf(ss[t][m] - mx); ss[t][m] = e; ps += e; }
      mrow[t] = mx; lrow[t] = lrow[t]*scl + ps; srow[t] = scl;
    }
    __syncthreads();
    for(int i = t; i < TQ*C; i += 256){
      int r = i/C, c = i%C;
      float o = os[r][c]*srow[r];
      for(int m = 0; m < TM; m++) o += ss[r][m]*vs[m][c];
      os[r][c] = o;
    }
    __syncthreads();
  }
  for(int i = t; i < TQ*C; i += 256){
    int r = i/C, c = i%C;
    size_t idx = ((size_t)p*N + q0+r)*C + c;
    float v = 0.5f*os[r][c]/lrow[r];
    ctxn[idx] = j ? (ctxn[idx] + v) : v;
  }
}

// ---------- LayerNorm over C, in place on ctxn rows [4*N][C] ----------
__global__ __launch_bounds__(256) void k_ln(float* __restrict__ ctxn, fp lng, fp lnb, int C){
  __shared__ float r1[4], r2[4];
  float* row = ctxn + (size_t)blockIdx.x*C;
  int t = threadIdx.x;
  float s = 0.f, s2 = 0.f;
  for(int c = t; c < C; c += 256){ float v = row[c]; s += v; s2 += v*v; }
  for(int o = 32; o > 0; o >>= 1){ s += __shfl_down(s, o); s2 += __shfl_down(s2, o); }
  if((t & 63) == 0){ r1[t>>6] = s; r2[t>>6] = s2; }
  __syncthreads();
  if(t == 0){
    float S = r1[0]+r1[1]+r1[2]+r1[3], S2 = r2[0]+r2[1]+r2[2]+r2[3];
    float m = S/(float)C, var = S2/(float)C - m*m;
    r1[0] = m; r2[0] = rsqrtf(var + 1e-5f);
  }
  __syncthreads();
  float m = r1[0], ri = r2[0];
  for(int c = t; c < C; c += 256) row[c] = (row[c] - m)*ri*lng[c] + lnb[c];
}

// ---------- cm[n][c] = mean_p ctxn[p][n][c] ----------
__global__ __launch_bounds__(256) void k_cm(const float* __restrict__ ctxn, float* __restrict__ cm,
                                            int C, int N){
  int n = blockIdx.x;
  for(int c = threadIdx.x; c < C; c += blockDim.x){
    float s = 0.25f*( ctxn[((size_t)0*N + n)*C + c] + ctxn[((size_t)1*N + n)*C + c]
                    + ctxn[((size_t)2*N + n)*C + c] + ctxn[((size_t)3*N + n)*C + c]);
    cm[(size_t)n*C + c] = s;
  }
}

// ---------- h[b][c][n] += cm[n][c]  (all 6 b) ----------
__global__ __launch_bounds__(256) void k_add(float* __restrict__ h, const float* __restrict__ cm,
                                             int C, int N){
  int bc = blockIdx.x; int c = bc % C;
  float* hp = h + (size_t)bc*N;
  for(int n = threadIdx.x; n < N; n += blockDim.x) hp[n] += cm[(size_t)n*C + c];
}

// ---------- batch-norm stats per channel over (b,n) ----------
__global__ __launch_bounds__(256) void k_bnstat(const float* __restrict__ h, fp bng, fp bnb,
                                                float* __restrict__ ssout, int C, int N){
  __shared__ float red[8], red2[8];
  int c = blockIdx.x; int t = threadIdx.x;
  float s = 0.f, s2 = 0.f;
  for(int b = 0; b < 6; b++){
    const float* hp = h + ((size_t)b*C + c)*N;
    for(int n = t; n < N; n += blockDim.x){ float v = hp[n]; s += v; s2 += v*v; }
  }
  for(int o = 32; o > 0; o >>= 1){ s += __shfl_down(s, o); s2 += __shfl_down(s2, o); }
  int lane = t & 63, wid = t >> 6;
  if(lane == 0){ red[wid] = s; red2[wid] = s2; }
  __syncthreads();
  if(t == 0){
    float S = 0.f, S2 = 0.f; int nw = blockDim.x >> 6;
    for(int i = 0; i < nw; i++){ S += red[i]; S2 += red2[i]; }
    float inv = 1.f/(6.f*(float)N);
    float m = S*inv, var = S2*inv - m*m;
    float sc = bng[c]*rsqrtf(var + 1e-5f);
    ssout[c] = sc; ssout[C + c] = bnb[c] - m*sc;
  }
}

// ---------- BN apply + ReLU, in place ----------
__global__ __launch_bounds__(256) void k_bnrelu(float* __restrict__ h, const float* __restrict__ ssin,
                                                int C, int N){
  int bc = blockIdx.x; int c = bc % C;
  float sc = ssin[c], sh = ssin[C + c];
  float* hp = h + (size_t)bc*N;
  for(int n = threadIdx.x; n < N; n += blockDim.x){
    float v = hp[n]*sc + sh; hp[n] = v > 0.f ? v : 0.f;
  }
}

// ---------- final up2 + f32 store ----------
__global__ __launch_bounds__(256) void k_up_out(const float* __restrict__ in, float* out,
                                                int H, int W){
  int bc = blockIdx.x;                     // b*64 + c
  const float* ip = in + (size_t)bc*H*W;
  float* op = out + (size_t)bc*4*H*W;
  int W2 = 2*W, N2 = 4*H*W;
  for(int p = threadIdx.x; p < N2; p += blockDim.x){
    int y = p / W2, x = p % W2;
    op[p] = ip[(y>>1)*W + (x>>1)];
  }
}

extern "C" void kernel_launch(void* const* d_in, const int* in_sizes, int n_in,
                              void* d_out, int out_size, void* d_ws, size_t ws_size,
                              hipStream_t stream){
  float* out_f = (float*)d_out;
  // ---- diagnostics: encode failure cause in absmax ----
  static const int EXP[36] = {294912,393216,786432,1572864,3538944,512,
    131072,256,262144,262144,262144,512,512,512,512,1179648,
    32768,128,65536,65536,65536,256,256,256,256,294912,
    8192,64,16384,16384,16384,128,128,128,128,73728};
  bool ok = (n_in == 36) && (out_size == 6291456);
  if(ok) for(int i = 0; i < 36; i++) if(in_sizes[i] != EXP[i]){ ok = false; break; }
  if(!ok){  // absmax ~ 13.3 => input order/sizes mismatch
    k_fill<<<(out_size+255)/256, 256, 0, stream>>>(out_f, out_size, 10.0f);
    return;
  }
  const size_t R = 3145728;                 // floats per region
  const size_t NEED = (5*R + 1024)*sizeof(float);   // 62,918,656 B
  if(ws_size < NEED){  // absmax ~ 103 => workspace too small
    k_fill<<<(out_size+255)/256, 256, 0, stream>>>(out_f, out_size, 100.0f);
    return;
  }
  (void)hipGetLastError();   // clear stale error state
  // launch-error sentinel: absmax ~ (code+3.3) identifies the failing group
  #define CKERR(code) do{ if(hipGetLastError() != hipSuccess){ \
      k_fill<<<(out_size+255)/256, 256, 0, stream>>>(out_f, out_size, (float)(code)); \
      return; } }while(0)

  fp x = (fp)d_in[0];
  fp skip[3]  = {(fp)d_in[1],(fp)d_in[2],(fp)d_in[3]};
  fp w_sc = (fp)d_in[4], b_sc = (fp)d_in[5];
  fp w_up[3] = {(fp)d_in[6], (fp)d_in[16],(fp)d_in[26]};
  fp b_up[3] = {(fp)d_in[7], (fp)d_in[17],(fp)d_in[27]};
  fp wq[3]   = {(fp)d_in[8], (fp)d_in[18],(fp)d_in[28]};
  fp wk[3]   = {(fp)d_in[9], (fp)d_in[19],(fp)d_in[29]};
  fp wv[3]   = {(fp)d_in[10],(fp)d_in[20],(fp)d_in[30]};
  fp lng[3]  = {(fp)d_in[11],(fp)d_in[21],(fp)d_in[31]};
  fp lnb[3]  = {(fp)d_in[12],(fp)d_in[22],(fp)d_in[32]};
  fp bng[3]  = {(fp)d_in[13],(fp)d_in[23],(fp)d_in[33]};
  fp bnb[3]  = {(fp)d_in[14],(fp)d_in[24],(fp)d_in[34]};
  fp w_cb[3] = {(fp)d_in[15],(fp)d_in[25],(fp)d_in[35]};

  // ---- arena: 5 regions of 3,145,728 floats + SS (liveness-verified r3) ----
  float* Wp = (float*)d_ws;
  float *Cc = Wp, *XT = Wp + R, *QB = Wp + 2*R, *KB = Wp + 3*R, *VB = Wp + 4*R;
  float *SS = Wp + 5*R;
  float *CT = XT, *OB = XT, *Bf = QB, *CM = QB;

  // stage 0: x -> h0 (in Cc), conv_sc -> OB [6,512,8,8]
  k_in_tr<<<dim3(64,6),256,0,stream>>>(x, Cc);
  k_conv3<<<6*512, 64, 768*9*4, stream>>>(Cc, w_sc, b_sc, OB, 768, 512, 8, 8);
  CKERR(20);

  const int Cskip[3] = {256,128,64};
  const int Hs[3]    = {16,32,64};
  int Cprev = 512;
  for(int i = 0; i < 3; i++){
    int H = Hs[i], N = H*H;
    int Cup = Cprev/2;
    int C = Cup + Cskip[i];
    k_up_conv1<<<6*Cup, 256, Cprev*4, stream>>>(OB, w_up[i], b_up[i], Bf, Cprev, Cup, H, H);
    k_concat<<<6*C, 256, 0, stream>>>(Bf, skip[i], Cc, Cup, Cskip[i], N);
    k_tr<<<dim3(N/32, C/32, 6), 256, 0, stream>>>(Cc, XT, C, N);
    k_proj<<<dim3(N,6), 256, C*4, stream>>>(XT, wq[i], wk[i], wv[i], QB, KB, VB, C, N);
    CKERR(30 + 10*i);
    for(int j = 0; j < 2; j++){
      if(i==0) k_attn_core<512, 4, 8><<<dim3(N/4 ,4),256,0,stream>>>(QB,KB,VB,CT,N,j);
      if(i==1) k_attn_core<256, 8,16><<<dim3(N/8 ,4),256,0,stream>>>(QB,KB,VB,CT,N,j);
      if(i==2) k_attn_core<128,16,32><<<dim3(N/16,4),256,0,stream>>>(QB,KB,VB,CT,N,j);
    }
    k_ln<<<4*N, 256, 0, stream>>>(CT, lng[i], lnb[i], C);
    CKERR(32 + 10*i);
    k_cm<<<N, 256, 0, stream>>>(CT, CM, C, N);
    k_add<<<6*C, 256, 0, stream>>>(Cc, CM, C, N);
    k_bnstat<<<C, 256, 0, stream>>>(Cc, bng[i], bnb[i], SS, C, N);
    k_bnrelu<<<6*C, 256, 0, stream>>>(Cc, SS, C, N);
    k_conv3<<<6*(C/2), 256, C*9*4, stream>>>(Cc, w_cb[i], nullptr, OB, C, C/2, H, H);
    CKERR(34 + 10*i);
    Cprev = C/2;
  }
  k_up_out<<<6*64, 256, 0, stream>>>(OB, out_f, 64, 64);
  CKERR(90);
  #undef CKERR
}

// Round 6
// 7611.185 us; speedup vs baseline: 1.4893x; 1.4893x over previous
//
#include <hip/hip_runtime.h>
#include <hip/hip_bf16.h>

typedef const float* fp;
typedef __attribute__((ext_vector_type(8))) short short8v;   // 8 bf16 (4 VGPR)
typedef __attribute__((ext_vector_type(4))) float f32x4;

__device__ __forceinline__ unsigned short f2b(float f){       // f32 -> bf16 RNE
  union{float f; unsigned u;} x; x.f = f;
  unsigned r = x.u + 0x7FFFu + ((x.u>>16)&1u);
  return (unsigned short)(r>>16);
}

// ---------- sentinel fill (diagnostic channel via absmax) ----------
__global__ __launch_bounds__(256) void k_fill(float* out, int n, float v){
  int i = blockIdx.x*256 + threadIdx.x;
  if(i < n) out[i] = v;
}

// ---------- input transpose: x [6,64,768] f32 -> h0 [6,768,64] f32 ----------
__global__ __launch_bounds__(256) void k_in_tr(fp x, float* h0){
  int n = blockIdx.x, b = blockIdx.y;
  for(int d = threadIdx.x; d < 768; d += blockDim.x)
    h0[((size_t)b*768 + d)*64 + n] = x[((size_t)b*64 + n)*768 + d];
}

// ---------- direct 3x3 SAME conv, weights staged in LDS ----------
__global__ __launch_bounds__(256) void k_conv3(const float* __restrict__ in, fp w, fp bias,
                                               float* __restrict__ out,
                                               int Cin, int Cout, int H, int W){
  int bc = blockIdx.x; int b = bc / Cout; int co = bc % Cout;
  extern __shared__ float ws[];            // Cin*9 floats
  int nw = Cin*9;
  for(int i = threadIdx.x; i < nw; i += blockDim.x) ws[i] = w[(size_t)co*nw + i];
  __syncthreads();
  int N = H*W;
  const float* inb = in + (size_t)b*Cin*N;
  float bv = bias ? bias[co] : 0.f;
  for(int p = threadIdx.x; p < N; p += blockDim.x){
    int y = p / W, x = p % W;
    float acc = bv;
    for(int ci = 0; ci < Cin; ci++){
      const float* ip = inb + (size_t)ci*N;
      const float* wp = ws + ci*9;
      for(int ky = 0; ky < 3; ky++){
        int yy = y + ky - 1; if((unsigned)yy >= (unsigned)H) continue;
        const float* row = ip + yy*W;
        for(int kx = 0; kx < 3; kx++){
          int xx = x + kx - 1; if((unsigned)xx >= (unsigned)W) continue;
          acc += row[xx] * wp[ky*3+kx];
        }
      }
    }
    out[((size_t)b*Cout + co)*N + p] = acc;
  }
}

// ---------- fused up2 + 1x1 conv (+bias) ----------
__global__ __launch_bounds__(256) void k_up_conv1(const float* __restrict__ in, fp w, fp bias,
                                                  float* __restrict__ out,
                                                  int Cin, int Cout, int H2, int W2){
  int bc = blockIdx.x; int b = bc / Cout; int co = bc % Cout;
  extern __shared__ float ws[];
  for(int i = threadIdx.x; i < Cin; i += blockDim.x) ws[i] = w[(size_t)co*Cin + i];
  __syncthreads();
  int N2 = H2*W2, W1 = W2/2, N1 = (H2/2)*W1;
  const float* inb = in + (size_t)b*Cin*N1;
  float bv = bias[co];
  for(int p = threadIdx.x; p < N2; p += blockDim.x){
    int y = p / W2, x = p % W2;
    int q = (y>>1)*W1 + (x>>1);
    float acc = bv;
    for(int ci = 0; ci < Cin; ci++) acc += inb[(size_t)ci*N1 + q] * ws[ci];
    out[((size_t)b*Cout + co)*N2 + p] = acc;
  }
}

// ---------- concat channels: [a ; skip] -> cat f32 ----------
__global__ __launch_bounds__(256) void k_concat(const float* __restrict__ a, fp skip,
                                                float* __restrict__ cat, int Ca, int Cs, int N){
  int bc = blockIdx.x; int C = Ca + Cs; int b = bc / C; int c = bc % C;
  float* o = cat + (size_t)bc*N;
  if(c < Ca){
    const float* s = a + ((size_t)b*Ca + c)*N;
    for(int n = threadIdx.x; n < N; n += blockDim.x) o[n] = s[n];
  }else{
    fp s = skip + ((size_t)b*Cs + (c-Ca))*N;
    for(int n = threadIdx.x; n < N; n += blockDim.x) o[n] = s[n];
  }
}

// ---------- tiled transpose [6][C][N] -> [6][N][C] ----------
__global__ __launch_bounds__(256) void k_tr(const float* __restrict__ src, float* __restrict__ dst,
                                            int C, int N){
  __shared__ float t[32][33];
  int b = blockIdx.z;
  int c0 = blockIdx.y*32, n0 = blockIdx.x*32;
  int tx = threadIdx.x & 31, ty = threadIdx.x >> 5;
  for(int i = ty; i < 32; i += 8) t[i][tx] = src[((size_t)b*C + c0+i)*N + n0+tx];
  __syncthreads();
  for(int i = ty; i < 32; i += 8) dst[((size_t)b*N + n0+i)*C + c0+tx] = t[tx][i];
}

// ---------- QKV projection -> bf16 Q (pre-scaled by 1/sqrt(C)), K, V ----------
__global__ __launch_bounds__(256) void k_projb(const float* __restrict__ xt, fp wq, fp wk, fp wv,
                                               unsigned short* __restrict__ Q,
                                               unsigned short* __restrict__ K,
                                               unsigned short* __restrict__ V, int C, int N){
  int b = blockIdx.y, n = blockIdx.x;
  extern __shared__ float xs[];
  const float* xp = xt + ((size_t)b*N + n)*C;
  for(int c = threadIdx.x; c < C; c += blockDim.x) xs[c] = xp[c];
  __syncthreads();
  float rs = rsqrtf((float)C);
  for(int c = threadIdx.x; c < C; c += blockDim.x){
    float aq = 0.f, ak = 0.f, av = 0.f;
    for(int cc = 0; cc < C; cc++){
      float xv = xs[cc];
      aq += xv * wq[(size_t)cc*C + c];
      ak += xv * wk[(size_t)cc*C + c];
      av += xv * wv[(size_t)cc*C + c];
    }
    size_t o = ((size_t)b*N + n)*C + c;
    Q[o] = f2b(aq*rs); K[o] = f2b(ak); V[o] = f2b(av);
  }
}

// ---------- MFMA flash attention, one neighbor j: ctxn (+)= 0.5*softmax(QK^T)V ----------
// wave owns 16 queries. K tile [32][C] + V^T tile [C][32] in XOR-swizzled LDS.
// mfma_f32_16x16x32_bf16: A/B lane l: row=l&15, k=8*(l>>4)+i ; D: col=l&15, row=4*(l>>4)+reg.
template<int C>
__global__ __launch_bounds__(256) void k_attn_mfma(const unsigned short* __restrict__ Q,
                                                   const unsigned short* __restrict__ K,
                                                   const unsigned short* __restrict__ V,
                                                   float* __restrict__ ctxn, int N, int j){
  __shared__ unsigned short Ks[32*C];      // swz: idx ^ ((m&7)<<3)
  __shared__ unsigned short Vt[C*32];      // swz: idx ^ ((c&3)<<3)
  __shared__ unsigned short ps[4][16*32];  // per-wave P tile, swz: idx ^ ((m&3)<<3)
  int t = threadIdx.x, wid = t>>6, lane = t&63;
  int l15 = lane&15, g = lane>>4;
  int p = blockIdx.y;
  int q0 = (blockIdx.x*4 + wid)*16;
  const unsigned short* Qb = Q + ((size_t)(p+1)*N + q0)*C;
  const unsigned short* Kb = K + (size_t)(p + (j?2:0))*N*C;
  const unsigned short* Vb = V + (size_t)(p + (j?2:0))*N*C;

  short8v qf[C/32];
  #pragma unroll
  for(int kk = 0; kk < C/32; kk++)
    qf[kk] = *(const short8v*)(Qb + (size_t)l15*C + kk*32 + 8*g);

  f32x4 acc[C/16];
  #pragma unroll
  for(int i = 0; i < C/16; i++) acc[i] = f32x4{0.f,0.f,0.f,0.f};
  float mrow[4] = {-1e30f,-1e30f,-1e30f,-1e30f};
  float lrow[4] = {0.f,0.f,0.f,0.f};

  for(int m0 = 0; m0 < N; m0 += 32){
    __syncthreads();
    // stage K[32][C] and Vt[C][32] (bf16, swizzled)
    for(int idx = t*8; idx < 32*C; idx += 256*8){
      int m = idx/C, c = idx%C;
      short8v kv = *(const short8v*)(Kb + (size_t)(m0+m)*C + c);
      short8v vv = *(const short8v*)(Vb + (size_t)(m0+m)*C + c);
      *(short8v*)(Ks + ((m*C + c) ^ ((m&7)<<3))) = kv;
      #pragma unroll
      for(int e = 0; e < 8; e++)
        Vt[((c+e)*32 + m) ^ (((c+e)&3)<<3)] = ((unsigned short*)&vv)[e];
    }
    __syncthreads();
    // S = Q K^T : n-halves 0..15 (s0) and 16..31 (s1)
    f32x4 s0 = {0.f,0.f,0.f,0.f}, s1 = {0.f,0.f,0.f,0.f};
    #pragma unroll
    for(int kk = 0; kk < C/32; kk++){
      short8v k0 = *(const short8v*)(Ks + ((l15*C      + kk*32 + 8*g) ^ ((l15&7)<<3)));
      short8v k1 = *(const short8v*)(Ks + (((16+l15)*C + kk*32 + 8*g) ^ ((l15&7)<<3)));
      s0 = __builtin_amdgcn_mfma_f32_16x16x32_bf16(qf[kk], k0, s0, 0,0,0);
      s1 = __builtin_amdgcn_mfma_f32_16x16x32_bf16(qf[kk], k1, s1, 0,0,0);
    }
    // online softmax: row m=4g+r lives in reg r; keys spread across 16 lanes (+2 frags)
    float scl[4];
    #pragma unroll
    for(int r = 0; r < 4; r++){
      float mx = fmaxf(s0[r], s1[r]);
      #pragma unroll
      for(int off = 1; off < 16; off <<= 1) mx = fmaxf(mx, __shfl_xor(mx, off));
      float mnew = fmaxf(mrow[r], mx);
      scl[r] = __expf(mrow[r] - mnew);
      float e0 = __expf(s0[r] - mnew), e1 = __expf(s1[r] - mnew);
      float psum = e0 + e1;
      #pragma unroll
      for(int off = 1; off < 16; off <<= 1) psum += __shfl_xor(psum, off);
      lrow[r] = lrow[r]*scl[r] + psum;
      mrow[r] = mnew;
      int m = 4*g + r;
      ps[wid][(m*32 + l15)      ^ ((m&3)<<3)] = f2b(e0);
      ps[wid][(m*32 + 16 + l15) ^ ((m&3)<<3)] = f2b(e1);
    }
    #pragma unroll
    for(int ct = 0; ct < C/16; ct++){
      #pragma unroll
      for(int r = 0; r < 4; r++) acc[ct][r] *= scl[r];
    }
    // PV: A = P tile (per-wave), B = Vt
    short8v pa = *(const short8v*)(ps[wid] + ((l15*32 + 8*g) ^ ((l15&3)<<3)));
    #pragma unroll
    for(int ct = 0; ct < C/16; ct++){
      short8v vb = *(const short8v*)(Vt + (((ct*16+l15)*32 + 8*g) ^ ((l15&3)<<3)));
      acc[ct] = __builtin_amdgcn_mfma_f32_16x16x32_bf16(pa, vb, acc[ct], 0,0,0);
    }
  }
  // write: lane holds ctx[m=4g+r][c=ct*16+l15]
  #pragma unroll
  for(int ct = 0; ct < C/16; ct++){
    int c = ct*16 + l15;
    #pragma unroll
    for(int r = 0; r < 4; r++){
      int m = 4*g + r;
      size_t idx = ((size_t)p*N + q0 + m)*C + c;
      float v = 0.5f*acc[ct][r]/lrow[r];
      if(j) ctxn[idx] += v; else ctxn[idx] = v;
    }
  }
}

// ---------- LayerNorm over C, in place on ctxn rows [4*N][C] ----------
__global__ __launch_bounds__(256) void k_ln(float* __restrict__ ctxn, fp lng, fp lnb, int C){
  __shared__ float r1[4], r2[4];
  float* row = ctxn + (size_t)blockIdx.x*C;
  int t = threadIdx.x;
  float s = 0.f, s2 = 0.f;
  for(int c = t; c < C; c += 256){ float v = row[c]; s += v; s2 += v*v; }
  for(int o = 32; o > 0; o >>= 1){ s += __shfl_down(s, o); s2 += __shfl_down(s2, o); }
  if((t & 63) == 0){ r1[t>>6] = s; r2[t>>6] = s2; }
  __syncthreads();
  if(t == 0){
    float S = r1[0]+r1[1]+r1[2]+r1[3], S2 = r2[0]+r2[1]+r2[2]+r2[3];
    float m = S/(float)C, var = S2/(float)C - m*m;
    r1[0] = m; r2[0] = rsqrtf(var + 1e-5f);
  }
  __syncthreads();
  float m = r1[0], ri = r2[0];
  for(int c = t; c < C; c += 256) row[c] = (row[c] - m)*ri*lng[c] + lnb[c];
}

// ---------- cm[n][c] = mean_p ctxn[p][n][c] ----------
__global__ __launch_bounds__(256) void k_cm(const float* __restrict__ ctxn, float* __restrict__ cm,
                                            int C, int N){
  int n = blockIdx.x;
  for(int c = threadIdx.x; c < C; c += blockDim.x){
    float s = 0.25f*( ctxn[((size_t)0*N + n)*C + c] + ctxn[((size_t)1*N + n)*C + c]
                    + ctxn[((size_t)2*N + n)*C + c] + ctxn[((size_t)3*N + n)*C + c]);
    cm[(size_t)n*C + c] = s;
  }
}

// ---------- h[b][c][n] += cm[n][c] ----------
__global__ __launch_bounds__(256) void k_add(float* __restrict__ h, const float* __restrict__ cm,
                                             int C, int N){
  int bc = blockIdx.x; int c = bc % C;
  float* hp = h + (size_t)bc*N;
  for(int n = threadIdx.x; n < N; n += blockDim.x) hp[n] += cm[(size_t)n*C + c];
}

// ---------- batch-norm stats per channel over (b,n) ----------
__global__ __launch_bounds__(256) void k_bnstat(const float* __restrict__ h, fp bng, fp bnb,
                                                float* __restrict__ ssout, int C, int N){
  __shared__ float red[8], red2[8];
  int c = blockIdx.x; int t = threadIdx.x;
  float s = 0.f, s2 = 0.f;
  for(int b = 0; b < 6; b++){
    const float* hp = h + ((size_t)b*C + c)*N;
    for(int n = t; n < N; n += blockDim.x){ float v = hp[n]; s += v; s2 += v*v; }
  }
  for(int o = 32; o > 0; o >>= 1){ s += __shfl_down(s, o); s2 += __shfl_down(s2, o); }
  int lane = t & 63, wid = t >> 6;
  if(lane == 0){ red[wid] = s; red2[wid] = s2; }
  __syncthreads();
  if(t == 0){
    float S = 0.f, S2 = 0.f; int nw = blockDim.x >> 6;
    for(int i = 0; i < nw; i++){ S += red[i]; S2 += red2[i]; }
    float inv = 1.f/(6.f*(float)N);
    float m = S*inv, var = S2*inv - m*m;
    float sc = bng[c]*rsqrtf(var + 1e-5f);
    ssout[c] = sc; ssout[C + c] = bnb[c] - m*sc;
  }
}

// ---------- BN apply + ReLU, in place ----------
__global__ __launch_bounds__(256) void k_bnrelu(float* __restrict__ h, const float* __restrict__ ssin,
                                                int C, int N){
  int bc = blockIdx.x; int c = bc % C;
  float sc = ssin[c], sh = ssin[C + c];
  float* hp = h + (size_t)bc*N;
  for(int n = threadIdx.x; n < N; n += blockDim.x){
    float v = hp[n]*sc + sh; hp[n] = v > 0.f ? v : 0.f;
  }
}

// ---------- final up2 + f32 store ----------
__global__ __launch_bounds__(256) void k_up_out(const float* __restrict__ in, float* out,
                                                int H, int W){
  int bc = blockIdx.x;
  const float* ip = in + (size_t)bc*H*W;
  float* op = out + (size_t)bc*4*H*W;
  int W2 = 2*W, N2 = 4*H*W;
  for(int p = threadIdx.x; p < N2; p += blockDim.x){
    int y = p / W2, x = p % W2;
    op[p] = ip[(y>>1)*W + (x>>1)];
  }
}

extern "C" void kernel_launch(void* const* d_in, const int* in_sizes, int n_in,
                              void* d_out, int out_size, void* d_ws, size_t ws_size,
                              hipStream_t stream){
  float* out_f = (float*)d_out;
  static const int EXP[36] = {294912,393216,786432,1572864,3538944,512,
    131072,256,262144,262144,262144,512,512,512,512,1179648,
    32768,128,65536,65536,65536,256,256,256,256,294912,
    8192,64,16384,16384,16384,128,128,128,128,73728};
  bool ok = (n_in == 36) && (out_size == 6291456);
  if(ok) for(int i = 0; i < 36; i++) if(in_sizes[i] != EXP[i]){ ok = false; break; }
  if(!ok){
    k_fill<<<(out_size+255)/256, 256, 0, stream>>>(out_f, out_size, 10.0f);
    return;
  }
  const size_t R = 3145728;
  const size_t NEED = (5*R + 1024)*sizeof(float);
  if(ws_size < NEED){
    k_fill<<<(out_size+255)/256, 256, 0, stream>>>(out_f, out_size, 100.0f);
    return;
  }
  (void)hipGetLastError();
  #define CKERR(code) do{ if(hipGetLastError() != hipSuccess){ \
      k_fill<<<(out_size+255)/256, 256, 0, stream>>>(out_f, out_size, (float)(code)); \
      return; } }while(0)

  fp x = (fp)d_in[0];
  fp skip[3]  = {(fp)d_in[1],(fp)d_in[2],(fp)d_in[3]};
  fp w_sc = (fp)d_in[4], b_sc = (fp)d_in[5];
  fp w_up[3] = {(fp)d_in[6], (fp)d_in[16],(fp)d_in[26]};
  fp b_up[3] = {(fp)d_in[7], (fp)d_in[17],(fp)d_in[27]};
  fp wq[3]   = {(fp)d_in[8], (fp)d_in[18],(fp)d_in[28]};
  fp wk[3]   = {(fp)d_in[9], (fp)d_in[19],(fp)d_in[29]};
  fp wv[3]   = {(fp)d_in[10],(fp)d_in[20],(fp)d_in[30]};
  fp lng[3]  = {(fp)d_in[11],(fp)d_in[21],(fp)d_in[31]};
  fp lnb[3]  = {(fp)d_in[12],(fp)d_in[22],(fp)d_in[32]};
  fp bng[3]  = {(fp)d_in[13],(fp)d_in[23],(fp)d_in[33]};
  fp bnb[3]  = {(fp)d_in[14],(fp)d_in[24],(fp)d_in[34]};
  fp w_cb[3] = {(fp)d_in[15],(fp)d_in[25],(fp)d_in[35]};

  float* Wp = (float*)d_ws;
  float *Cc = Wp, *XT = Wp + R;
  unsigned short *QB = (unsigned short*)(Wp + 2*R),
                 *KB = (unsigned short*)(Wp + 3*R),
                 *VB = (unsigned short*)(Wp + 4*R);
  float *SS = Wp + 5*R;
  float *CT = XT, *OB = XT, *Bf = Wp + 2*R, *CM = Wp + 2*R;  // aliases (liveness-verified r3)

  k_in_tr<<<dim3(64,6),256,0,stream>>>(x, Cc);
  k_conv3<<<6*512, 64, 768*9*4, stream>>>(Cc, w_sc, b_sc, OB, 768, 512, 8, 8);
  CKERR(20);

  const int Cskip[3] = {256,128,64};
  const int Hs[3]    = {16,32,64};
  int Cprev = 512;
  for(int i = 0; i < 3; i++){
    int H = Hs[i], N = H*H;
    int Cup = Cprev/2;
    int C = Cup + Cskip[i];
    k_up_conv1<<<6*Cup, 256, Cprev*4, stream>>>(OB, w_up[i], b_up[i], Bf, Cprev, Cup, H, H);
    k_concat<<<6*C, 256, 0, stream>>>(Bf, skip[i], Cc, Cup, Cskip[i], N);
    k_tr<<<dim3(N/32, C/32, 6), 256, 0, stream>>>(Cc, XT, C, N);
    k_projb<<<dim3(N,6), 256, C*4, stream>>>(XT, wq[i], wk[i], wv[i], QB, KB, VB, C, N);
    CKERR(30 + 10*i);
    for(int j = 0; j < 2; j++){
      if(i==0) k_attn_mfma<512><<<dim3(N/64,4),256,0,stream>>>(QB,KB,VB,CT,N,j);
      if(i==1) k_attn_mfma<256><<<dim3(N/64,4),256,0,stream>>>(QB,KB,VB,CT,N,j);
      if(i==2) k_attn_mfma<128><<<dim3(N/64,4),256,0,stream>>>(QB,KB,VB,CT,N,j);
    }
    k_ln<<<4*N, 256, 0, stream>>>(CT, lng[i], lnb[i], C);
    CKERR(32 + 10*i);
    k_cm<<<N, 256, 0, stream>>>(CT, CM, C, N);
    k_add<<<6*C, 256, 0, stream>>>(Cc, CM, C, N);
    k_bnstat<<<C, 256, 0, stream>>>(Cc, bng[i], bnb[i], SS, C, N);
    k_bnrelu<<<6*C, 256, 0, stream>>>(Cc, SS, C, N);
    k_conv3<<<6*(C/2), 256, C*9*4, stream>>>(Cc, w_cb[i], nullptr, OB, C, C/2, H, H);
    CKERR(34 + 10*i);
    Cprev = C/2;
  }
  k_up_out<<<6*64, 256, 0, stream>>>(OB, out_f, 64, 64);
  CKERR(90);
  #undef CKERR
}

// Round 7
// 2650.254 us; speedup vs baseline: 4.2770x; 2.8719x over previous
//
#include <hip/hip_runtime.h>
#include <hip/hip_bf16.h>

typedef const float* fp;
typedef __attribute__((ext_vector_type(8))) short short8v;   // 8 bf16 (4 VGPR)
typedef __attribute__((ext_vector_type(4))) float f32x4;

__device__ __forceinline__ unsigned short f2b(float f){       // f32 -> bf16 RNE
  union{float f; unsigned u;} x; x.f = f;
  unsigned r = x.u + 0x7FFFu + ((x.u>>16)&1u);
  return (unsigned short)(r>>16);
}

// ---------- sentinel fill (diagnostic channel via absmax) ----------
__global__ __launch_bounds__(256) void k_fill(float* out, int n, float v){
  int i = blockIdx.x*256 + threadIdx.x;
  if(i < n) out[i] = v;
}

// ---------- input transpose: x [6,64,768] f32 -> h0 [6,768,64] f32 ----------
__global__ __launch_bounds__(256) void k_in_tr(fp x, float* h0){
  int n = blockIdx.x, b = blockIdx.y;
  for(int d = threadIdx.x; d < 768; d += blockDim.x)
    h0[((size_t)b*768 + d)*64 + n] = x[((size_t)b*64 + n)*768 + d];
}

// ---------- implicit-im2col MFMA bf16 3x3 SAME conv ----------
// A = w[Cout][K=Cin*9] (row-major flatten == natural OIHW), B = im2col[K][N=H*W].
// Block: 256 thr = 4 waves; tile 64 co x 64 px. mfma_f32_16x16x32_bf16:
// A/B lane l: row/col=l&15, k=8*(l>>4)+i ; D: col=l&15, row=4*(l>>4)+reg.
__global__ __launch_bounds__(256) void k_conv3_mfma(const float* __restrict__ in,
                                                    fp w, fp bias,
                                                    float* __restrict__ out,
                                                    int Cin, int Cout, int H, int W){
  const int K = Cin*9, N = H*W;
  __shared__ unsigned short As[64*32];   // [co][k]  swz ^((row&3)<<3)
  __shared__ unsigned short Bs[64*32];   // [px][k]  swz ^((px&3)<<3)
  int t = threadIdx.x, wid = t>>6, lane = t&63, l15 = lane&15, g = lane>>4;
  int b = blockIdx.z;
  int co0 = blockIdx.y*64, px0 = blockIdx.x*64;
  const float* inb = in + (size_t)b*Cin*N;

  // staging assignments
  int arow = t>>2, acol = (t&3)*8;        // A: 8 consecutive k per thread
  int bkk = t>>3, bpx0 = (t&7)*8;         // B: one k, 8 consecutive px
  // precompute base pixel coords for B staging
  int ybase[8], xbase[8];
  #pragma unroll
  for(int e = 0; e < 8; e++){ int p = px0 + bpx0 + e; ybase[e] = p/W; xbase[e] = p%W; }

  f32x4 acc[4];
  #pragma unroll
  for(int i = 0; i < 4; i++) acc[i] = f32x4{0.f,0.f,0.f,0.f};

  for(int k0 = 0; k0 < K; k0 += 32){
    __syncthreads();
    { // stage A tile
      const float* wp = w + (size_t)(co0+arow)*K + k0 + acol;
      unsigned short tmp[8];
      #pragma unroll
      for(int e = 0; e < 8; e++) tmp[e] = f2b(wp[e]);
      *(short8v*)(As + ((arow*32 + acol) ^ ((arow&3)<<3))) = *(const short8v*)tmp;
    }
    { // stage B tile (im2col with zero pad)
      int k = k0 + bkk;
      int ci = k/9, tap = k - ci*9;
      int dy = tap/3 - 1, dx = tap - (tap/3)*3 - 1;
      const float* ip = inb + (size_t)ci*N;
      #pragma unroll
      for(int e = 0; e < 8; e++){
        int yy = ybase[e] + dy, xx = xbase[e] + dx;
        float v = ((unsigned)yy < (unsigned)H && (unsigned)xx < (unsigned)W)
                  ? ip[yy*W + xx] : 0.f;
        int px = bpx0 + e;
        Bs[(px*32 + bkk) ^ ((px&3)<<3)] = f2b(v);
      }
    }
    __syncthreads();
    short8v a = *(const short8v*)(As + (((wid*16+l15)*32 + 8*g) ^ ((l15&3)<<3)));
    #pragma unroll
    for(int pt = 0; pt < 4; pt++){
      short8v bf = *(const short8v*)(Bs + (((pt*16+l15)*32 + 8*g) ^ ((l15&3)<<3)));
      acc[pt] = __builtin_amdgcn_mfma_f32_16x16x32_bf16(a, bf, acc[pt], 0,0,0);
    }
  }
  #pragma unroll
  for(int pt = 0; pt < 4; pt++){
    #pragma unroll
    for(int r = 0; r < 4; r++){
      int co = co0 + wid*16 + 4*g + r;
      int p  = px0 + pt*16 + l15;
      float bv = bias ? bias[co] : 0.f;
      out[((size_t)b*Cout + co)*N + p] = acc[pt][r] + bv;
    }
  }
}

// ---------- 1x1 conv at LOW res (up2 commutes with 1x1 conv) ----------
__global__ __launch_bounds__(256) void k_conv1_low(const float* __restrict__ in, fp w, fp bias,
                                                   float* __restrict__ out,
                                                   int Cin, int Cout, int N1){
  int bc = blockIdx.x; int b = bc / Cout; int co = bc % Cout;
  extern __shared__ float ws[];
  for(int i = threadIdx.x; i < Cin; i += blockDim.x) ws[i] = w[(size_t)co*Cin + i];
  __syncthreads();
  const float* inb = in + (size_t)b*Cin*N1;
  float bv = bias[co];
  for(int p = threadIdx.x; p < N1; p += blockDim.x){
    float acc = bv;
    for(int ci = 0; ci < Cin; ci++) acc += inb[(size_t)ci*N1 + p] * ws[ci];
    out[((size_t)b*Cout + co)*N1 + p] = acc;
  }
}

// ---------- concat channels with up2 replication of low-res part ----------
__global__ __launch_bounds__(256) void k_concat_up(const float* __restrict__ a, fp skip,
                                                   float* __restrict__ cat,
                                                   int Ca, int Cs, int N2, int W2){
  int bc = blockIdx.x; int C = Ca + Cs; int b = bc / C; int c = bc % C;
  float* o = cat + (size_t)bc*N2;
  if(c < Ca){
    const float* s = a + ((size_t)b*Ca + c)*(N2/4);
    int W1 = W2/2;
    for(int n = threadIdx.x; n < N2; n += blockDim.x){
      int y = n / W2, x = n % W2;
      o[n] = s[(y>>1)*W1 + (x>>1)];
    }
  }else{
    fp s = skip + ((size_t)b*Cs + (c-Ca))*N2;
    for(int n = threadIdx.x; n < N2; n += blockDim.x) o[n] = s[n];
  }
}

// ---------- tiled transpose [6][C][N] -> [6][N][C] ----------
__global__ __launch_bounds__(256) void k_tr(const float* __restrict__ src, float* __restrict__ dst,
                                            int C, int N){
  __shared__ float t[32][33];
  int b = blockIdx.z;
  int c0 = blockIdx.y*32, n0 = blockIdx.x*32;
  int tx = threadIdx.x & 31, ty = threadIdx.x >> 5;
  for(int i = ty; i < 32; i += 8) t[i][tx] = src[((size_t)b*C + c0+i)*N + n0+tx];
  __syncthreads();
  for(int i = ty; i < 32; i += 8) dst[((size_t)b*N + n0+i)*C + c0+tx] = t[tx][i];
}

// ---------- QKV projection -> bf16 Q (pre-scaled by 1/sqrt(C)), K, V ----------
__global__ __launch_bounds__(256) void k_projb(const float* __restrict__ xt, fp wq, fp wk, fp wv,
                                               unsigned short* __restrict__ Q,
                                               unsigned short* __restrict__ K,
                                               unsigned short* __restrict__ V, int C, int N){
  int b = blockIdx.y, n = blockIdx.x;
  extern __shared__ float xs[];
  const float* xp = xt + ((size_t)b*N + n)*C;
  for(int c = threadIdx.x; c < C; c += blockDim.x) xs[c] = xp[c];
  __syncthreads();
  float rs = rsqrtf((float)C);
  for(int c = threadIdx.x; c < C; c += blockDim.x){
    float aq = 0.f, ak = 0.f, av = 0.f;
    for(int cc = 0; cc < C; cc++){
      float xv = xs[cc];
      aq += xv * wq[(size_t)cc*C + c];
      ak += xv * wk[(size_t)cc*C + c];
      av += xv * wv[(size_t)cc*C + c];
    }
    size_t o = ((size_t)b*N + n)*C + c;
    Q[o] = f2b(aq*rs); K[o] = f2b(ak); V[o] = f2b(av);
  }
}

// ---------- MFMA flash attention, one neighbor j: ctxn (+)= 0.5*softmax(QK^T)V ----------
template<int C>
__global__ __launch_bounds__(256) void k_attn_mfma(const unsigned short* __restrict__ Q,
                                                   const unsigned short* __restrict__ K,
                                                   const unsigned short* __restrict__ V,
                                                   float* __restrict__ ctxn, int N, int j){
  __shared__ unsigned short Ks[32*C];      // swz: idx ^ ((m&7)<<3)
  __shared__ unsigned short Vt[C*32];      // swz: idx ^ ((c&3)<<3)
  __shared__ unsigned short ps[4][16*32];  // per-wave P tile, swz: idx ^ ((m&3)<<3)
  int t = threadIdx.x, wid = t>>6, lane = t&63;
  int l15 = lane&15, g = lane>>4;
  int p = blockIdx.y;
  int q0 = (blockIdx.x*4 + wid)*16;
  const unsigned short* Qb = Q + ((size_t)(p+1)*N + q0)*C;
  const unsigned short* Kb = K + (size_t)(p + (j?2:0))*N*C;
  const unsigned short* Vb = V + (size_t)(p + (j?2:0))*N*C;

  short8v qf[C/32];
  #pragma unroll
  for(int kk = 0; kk < C/32; kk++)
    qf[kk] = *(const short8v*)(Qb + (size_t)l15*C + kk*32 + 8*g);

  f32x4 acc[C/16];
  #pragma unroll
  for(int i = 0; i < C/16; i++) acc[i] = f32x4{0.f,0.f,0.f,0.f};
  float mrow[4] = {-1e30f,-1e30f,-1e30f,-1e30f};
  float lrow[4] = {0.f,0.f,0.f,0.f};

  for(int m0 = 0; m0 < N; m0 += 32){
    __syncthreads();
    for(int idx = t*8; idx < 32*C; idx += 256*8){
      int m = idx/C, c = idx%C;
      short8v kv = *(const short8v*)(Kb + (size_t)(m0+m)*C + c);
      short8v vv = *(const short8v*)(Vb + (size_t)(m0+m)*C + c);
      *(short8v*)(Ks + ((m*C + c) ^ ((m&7)<<3))) = kv;
      #pragma unroll
      for(int e = 0; e < 8; e++)
        Vt[((c+e)*32 + m) ^ (((c+e)&3)<<3)] = ((unsigned short*)&vv)[e];
    }
    __syncthreads();
    f32x4 s0 = {0.f,0.f,0.f,0.f}, s1 = {0.f,0.f,0.f,0.f};
    #pragma unroll
    for(int kk = 0; kk < C/32; kk++){
      short8v k0 = *(const short8v*)(Ks + ((l15*C      + kk*32 + 8*g) ^ ((l15&7)<<3)));
      short8v k1 = *(const short8v*)(Ks + (((16+l15)*C + kk*32 + 8*g) ^ ((l15&7)<<3)));
      s0 = __builtin_amdgcn_mfma_f32_16x16x32_bf16(qf[kk], k0, s0, 0,0,0);
      s1 = __builtin_amdgcn_mfma_f32_16x16x32_bf16(qf[kk], k1, s1, 0,0,0);
    }
    float scl[4];
    #pragma unroll
    for(int r = 0; r < 4; r++){
      float mx = fmaxf(s0[r], s1[r]);
      #pragma unroll
      for(int off = 1; off < 16; off <<= 1) mx = fmaxf(mx, __shfl_xor(mx, off));
      float mnew = fmaxf(mrow[r], mx);
      scl[r] = __expf(mrow[r] - mnew);
      float e0 = __expf(s0[r] - mnew), e1 = __expf(s1[r] - mnew);
      float psum = e0 + e1;
      #pragma unroll
      for(int off = 1; off < 16; off <<= 1) psum += __shfl_xor(psum, off);
      lrow[r] = lrow[r]*scl[r] + psum;
      mrow[r] = mnew;
      int m = 4*g + r;
      ps[wid][(m*32 + l15)      ^ ((m&3)<<3)] = f2b(e0);
      ps[wid][(m*32 + 16 + l15) ^ ((m&3)<<3)] = f2b(e1);
    }
    #pragma unroll
    for(int ct = 0; ct < C/16; ct++){
      #pragma unroll
      for(int r = 0; r < 4; r++) acc[ct][r] *= scl[r];
    }
    short8v pa = *(const short8v*)(ps[wid] + ((l15*32 + 8*g) ^ ((l15&3)<<3)));
    #pragma unroll
    for(int ct = 0; ct < C/16; ct++){
      short8v vb = *(const short8v*)(Vt + (((ct*16+l15)*32 + 8*g) ^ ((l15&3)<<3)));
      acc[ct] = __builtin_amdgcn_mfma_f32_16x16x32_bf16(pa, vb, acc[ct], 0,0,0);
    }
  }
  #pragma unroll
  for(int ct = 0; ct < C/16; ct++){
    int c = ct*16 + l15;
    #pragma unroll
    for(int r = 0; r < 4; r++){
      int m = 4*g + r;
      size_t idx = ((size_t)p*N + q0 + m)*C + c;
      float v = 0.5f*acc[ct][r]/lrow[r];
      if(j) ctxn[idx] += v; else ctxn[idx] = v;
    }
  }
}

// ---------- LayerNorm over C, in place on ctxn rows [4*N][C] ----------
__global__ __launch_bounds__(256) void k_ln(float* __restrict__ ctxn, fp lng, fp lnb, int C){
  __shared__ float r1[4], r2[4];
  float* row = ctxn + (size_t)blockIdx.x*C;
  int t = threadIdx.x;
  float s = 0.f, s2 = 0.f;
  for(int c = t; c < C; c += 256){ float v = row[c]; s += v; s2 += v*v; }
  for(int o = 32; o > 0; o >>= 1){ s += __shfl_down(s, o); s2 += __shfl_down(s2, o); }
  if((t & 63) == 0){ r1[t>>6] = s; r2[t>>6] = s2; }
  __syncthreads();
  if(t == 0){
    float S = r1[0]+r1[1]+r1[2]+r1[3], S2 = r2[0]+r2[1]+r2[2]+r2[3];
    float m = S/(float)C, var = S2/(float)C - m*m;
    r1[0] = m; r2[0] = rsqrtf(var + 1e-5f);
  }
  __syncthreads();
  float m = r1[0], ri = r2[0];
  for(int c = t; c < C; c += 256) row[c] = (row[c] - m)*ri*lng[c] + lnb[c];
}

// ---------- cm[n][c] = mean_p ctxn[p][n][c] ----------
__global__ __launch_bounds__(256) void k_cm(const float* __restrict__ ctxn, float* __restrict__ cm,
                                            int C, int N){
  int n = blockIdx.x;
  for(int c = threadIdx.x; c < C; c += blockDim.x){
    float s = 0.25f*( ctxn[((size_t)0*N + n)*C + c] + ctxn[((size_t)1*N + n)*C + c]
                    + ctxn[((size_t)2*N + n)*C + c] + ctxn[((size_t)3*N + n)*C + c]);
    cm[(size_t)n*C + c] = s;
  }
}

// ---------- h[b][c][n] += cm[n][c] ----------
__global__ __launch_bounds__(256) void k_add(float* __restrict__ h, const float* __restrict__ cm,
                                             int C, int N){
  int bc = blockIdx.x; int c = bc % C;
  float* hp = h + (size_t)bc*N;
  for(int n = threadIdx.x; n < N; n += blockDim.x) hp[n] += cm[(size_t)n*C + c];
}

// ---------- batch-norm stats per channel over (b,n) ----------
__global__ __launch_bounds__(256) void k_bnstat(const float* __restrict__ h, fp bng, fp bnb,
                                                float* __restrict__ ssout, int C, int N){
  __shared__ float red[8], red2[8];
  int c = blockIdx.x; int t = threadIdx.x;
  float s = 0.f, s2 = 0.f;
  for(int b = 0; b < 6; b++){
    const float* hp = h + ((size_t)b*C + c)*N;
    for(int n = t; n < N; n += blockDim.x){ float v = hp[n]; s += v; s2 += v*v; }
  }
  for(int o = 32; o > 0; o >>= 1){ s += __shfl_down(s, o); s2 += __shfl_down(s2, o); }
  int lane = t & 63, wid = t >> 6;
  if(lane == 0){ red[wid] = s; red2[wid] = s2; }
  __syncthreads();
  if(t == 0){
    float S = 0.f, S2 = 0.f; int nw = blockDim.x >> 6;
    for(int i = 0; i < nw; i++){ S += red[i]; S2 += red2[i]; }
    float inv = 1.f/(6.f*(float)N);
    float m = S*inv, var = S2*inv - m*m;
    float sc = bng[c]*rsqrtf(var + 1e-5f);
    ssout[c] = sc; ssout[C + c] = bnb[c] - m*sc;
  }
}

// ---------- BN apply + ReLU, in place ----------
__global__ __launch_bounds__(256) void k_bnrelu(float* __restrict__ h, const float* __restrict__ ssin,
                                                int C, int N){
  int bc = blockIdx.x; int c = bc % C;
  float sc = ssin[c], sh = ssin[C + c];
  float* hp = h + (size_t)bc*N;
  for(int n = threadIdx.x; n < N; n += blockDim.x){
    float v = hp[n]*sc + sh; hp[n] = v > 0.f ? v : 0.f;
  }
}

// ---------- final up2 + f32 store ----------
__global__ __launch_bounds__(256) void k_up_out(const float* __restrict__ in, float* out,
                                                int H, int W){
  int bc = blockIdx.x;
  const float* ip = in + (size_t)bc*H*W;
  float* op = out + (size_t)bc*4*H*W;
  int W2 = 2*W, N2 = 4*H*W;
  for(int p = threadIdx.x; p < N2; p += blockDim.x){
    int y = p / W2, x = p % W2;
    op[p] = ip[(y>>1)*W + (x>>1)];
  }
}

extern "C" void kernel_launch(void* const* d_in, const int* in_sizes, int n_in,
                              void* d_out, int out_size, void* d_ws, size_t ws_size,
                              hipStream_t stream){
  float* out_f = (float*)d_out;
  static const int EXP[36] = {294912,393216,786432,1572864,3538944,512,
    131072,256,262144,262144,262144,512,512,512,512,1179648,
    32768,128,65536,65536,65536,256,256,256,256,294912,
    8192,64,16384,16384,16384,128,128,128,128,73728};
  bool ok = (n_in == 36) && (out_size == 6291456);
  if(ok) for(int i = 0; i < 36; i++) if(in_sizes[i] != EXP[i]){ ok = false; break; }
  if(!ok){
    k_fill<<<(out_size+255)/256, 256, 0, stream>>>(out_f, out_size, 10.0f);
    return;
  }
  const size_t R = 3145728;
  const size_t NEED = (5*R + 1024)*sizeof(float);
  if(ws_size < NEED){
    k_fill<<<(out_size+255)/256, 256, 0, stream>>>(out_f, out_size, 100.0f);
    return;
  }
  (void)hipGetLastError();
  #define CKERR(code) do{ if(hipGetLastError() != hipSuccess){ \
      k_fill<<<(out_size+255)/256, 256, 0, stream>>>(out_f, out_size, (float)(code)); \
      return; } }while(0)

  fp x = (fp)d_in[0];
  fp skip[3]  = {(fp)d_in[1],(fp)d_in[2],(fp)d_in[3]};
  fp w_sc = (fp)d_in[4], b_sc = (fp)d_in[5];
  fp w_up[3] = {(fp)d_in[6], (fp)d_in[16],(fp)d_in[26]};
  fp b_up[3] = {(fp)d_in[7], (fp)d_in[17],(fp)d_in[27]};
  fp wq[3]   = {(fp)d_in[8], (fp)d_in[18],(fp)d_in[28]};
  fp wk[3]   = {(fp)d_in[9], (fp)d_in[19],(fp)d_in[29]};
  fp wv[3]   = {(fp)d_in[10],(fp)d_in[20],(fp)d_in[30]};
  fp lng[3]  = {(fp)d_in[11],(fp)d_in[21],(fp)d_in[31]};
  fp lnb[3]  = {(fp)d_in[12],(fp)d_in[22],(fp)d_in[32]};
  fp bng[3]  = {(fp)d_in[13],(fp)d_in[23],(fp)d_in[33]};
  fp bnb[3]  = {(fp)d_in[14],(fp)d_in[24],(fp)d_in[34]};
  fp w_cb[3] = {(fp)d_in[15],(fp)d_in[25],(fp)d_in[35]};

  float* Wp = (float*)d_ws;
  float *Cc = Wp, *XT = Wp + R;
  unsigned short *QB = (unsigned short*)(Wp + 2*R),
                 *KB = (unsigned short*)(Wp + 3*R),
                 *VB = (unsigned short*)(Wp + 4*R);
  float *SS = Wp + 5*R;
  float *CT = XT, *OB = XT, *Bf = Wp + 2*R, *CM = Wp + 2*R;  // aliases (liveness-verified r3)

  // stage 0: x -> h0 (in Cc), conv_sc (MFMA) -> OB [6,512,8,8]
  k_in_tr<<<dim3(64,6),256,0,stream>>>(x, Cc);
  k_conv3_mfma<<<dim3(1,8,6), 256, 0, stream>>>(Cc, w_sc, b_sc, OB, 768, 512, 8, 8);
  CKERR(20);

  const int Cskip[3] = {256,128,64};
  const int Hs[3]    = {16,32,64};
  int Cprev = 512;
  for(int i = 0; i < 3; i++){
    int H = Hs[i], N = H*H;
    int N1 = N/4;                      // low-res pixel count
    int Cup = Cprev/2;
    int C = Cup + Cskip[i];
    // 1x1 conv at low res (commutes with up2), then fused up2+concat
    k_conv1_low<<<6*Cup, 256, Cprev*4, stream>>>(OB, w_up[i], b_up[i], Bf, Cprev, Cup, N1);
    k_concat_up<<<6*C, 256, 0, stream>>>(Bf, skip[i], Cc, Cup, Cskip[i], N, H);
    k_tr<<<dim3(N/32, C/32, 6), 256, 0, stream>>>(Cc, XT, C, N);
    k_projb<<<dim3(N,6), 256, C*4, stream>>>(XT, wq[i], wk[i], wv[i], QB, KB, VB, C, N);
    CKERR(30 + 10*i);
    for(int j = 0; j < 2; j++){
      if(i==0) k_attn_mfma<512><<<dim3(N/64,4),256,0,stream>>>(QB,KB,VB,CT,N,j);
      if(i==1) k_attn_mfma<256><<<dim3(N/64,4),256,0,stream>>>(QB,KB,VB,CT,N,j);
      if(i==2) k_attn_mfma<128><<<dim3(N/64,4),256,0,stream>>>(QB,KB,VB,CT,N,j);
    }
    k_ln<<<4*N, 256, 0, stream>>>(CT, lng[i], lnb[i], C);
    CKERR(32 + 10*i);
    k_cm<<<N, 256, 0, stream>>>(CT, CM, C, N);
    k_add<<<6*C, 256, 0, stream>>>(Cc, CM, C, N);
    k_bnstat<<<C, 256, 0, stream>>>(Cc, bng[i], bnb[i], SS, C, N);
    k_bnrelu<<<6*C, 256, 0, stream>>>(Cc, SS, C, N);
    k_conv3_mfma<<<dim3(N/64, (C/2)/64, 6), 256, 0, stream>>>(Cc, w_cb[i], nullptr, OB, C, C/2, H, H);
    CKERR(34 + 10*i);
    Cprev = C/2;
  }
  k_up_out<<<6*64, 256, 0, stream>>>(OB, out_f, 64, 64);
  CKERR(90);
  #undef CKERR
}

// Round 8
// 1839.865 us; speedup vs baseline: 6.1608x; 1.4405x over previous
//
#include <hip/hip_runtime.h>
#include <hip/hip_bf16.h>

typedef const float* fp;
typedef __attribute__((ext_vector_type(8))) short short8v;   // 8 bf16 (4 VGPR)
typedef __attribute__((ext_vector_type(4))) float f32x4;

__device__ __forceinline__ unsigned short f2b(float f){       // f32 -> bf16 RNE
  union{float f; unsigned u;} x; x.f = f;
  unsigned r = x.u + 0x7FFFu + ((x.u>>16)&1u);
  return (unsigned short)(r>>16);
}

// ---------- sentinel fill ----------
__global__ __launch_bounds__(256) void k_fill(float* out, int n, float v){
  int i = blockIdx.x*256 + threadIdx.x;
  if(i < n) out[i] = v;
}
// ---------- per-channel bias fill: out[b][co][n] = bias[co] ----------
__global__ __launch_bounds__(256) void k_fillb(float* out, fp bias, int Cout, int N){
  int i = blockIdx.x*256 + threadIdx.x;
  if(i < 6*Cout*N) out[i] = bias[(i/N)%Cout];
}
// ---------- f32 -> bf16 elementwise (n mult of 8) ----------
__global__ __launch_bounds__(256) void k_b16(fp in, unsigned short* o, int n){
  int i = (blockIdx.x*256 + threadIdx.x)*8;
  if(i >= n) return;
  unsigned short tmp[8];
  #pragma unroll
  for(int e=0;e<8;e++) tmp[e] = f2b(in[i+e]);
  *(short8v*)(o+i) = *(const short8v*)tmp;
}
// ---------- weight transform: w[Cout][Cin][9] f32 -> wt[9][Cout][Cin] bf16 ----------
__global__ __launch_bounds__(256) void k_wtr(fp w, unsigned short* wt, int Cout, int Cin){
  int idx = blockIdx.x*256 + threadIdx.x;
  int cc = Cout*Cin;
  if(idx >= 9*cc) return;
  int tap = idx / cc;
  int rem = idx - tap*cc;
  wt[idx] = f2b(w[(size_t)rem*9 + tap]);
}

// ---------- input transpose: x [6,64,768] f32 -> h0 [6,768,64] f32 ----------
__global__ __launch_bounds__(256) void k_in_tr(fp x, float* h0){
  int n = blockIdx.x, b = blockIdx.y;
  for(int d = threadIdx.x; d < 768; d += blockDim.x)
    h0[((size_t)b*768 + d)*64 + n] = x[((size_t)b*64 + n)*768 + d];
}

// ---------- tap-decomposed implicit-GEMM MFMA 3x3 conv, split-K ----------
// wt[9][Cout][Cin] bf16, in bf16 [b][Cin][N]. grid (N/64, Cout/64, 6*S).
// LDS tiles [64][40] padded rows (bank stride 4 -> <=2-way). Register prefetch.
__global__ __launch_bounds__(256) void k_conv3_mfma2(const unsigned short* __restrict__ wt,
    const unsigned short* __restrict__ inb16, float* __restrict__ out,
    int Cin, int Cout, int H, int W, int S){
  const int N = H*W;
  __shared__ unsigned short As[64*40];
  __shared__ unsigned short Bs[64*40];
  int t = threadIdx.x, wid = t>>6, lane = t&63, l15 = lane&15, g = lane>>4;
  int b = blockIdx.z / S, s = blockIdx.z % S;
  int co0 = blockIdx.y*64, px0 = blockIdx.x*64;
  int ciN = Cin/S, ci0 = s*ciN;
  const unsigned short* inb = inb16 + (size_t)b*Cin*N;
  int arow = t>>2, acol = (t&3)*8;          // A role: one co row, 8 ci
  int bpx = t&63, boct = t>>6;              // B role: one pixel, 8 ci
  int p = px0 + bpx, py = p/W, px_ = p - py*W;
  int nc = ciN >> 5, nk = 9*nc;
  f32x4 acc[4];
  #pragma unroll
  for(int i=0;i<4;i++) acc[i] = f32x4{0.f,0.f,0.f,0.f};
  short8v av; unsigned short bt[8];

  #define PREF(ks) { int tap = (ks)/nc; int c0 = ((ks) - tap*nc)<<5;                     \
      int dy = tap/3 - 1, dx = tap - (tap/3)*3 - 1;                                      \
      av = *(const short8v*)(wt + ((size_t)tap*Cout + co0 + arow)*Cin + ci0 + c0 + acol);\
      bool val = ((unsigned)(py+dy) < (unsigned)H) && ((unsigned)(px_+dx) < (unsigned)W);\
      const unsigned short* bp = inb + (size_t)(ci0 + c0 + boct*8)*N + (p + dy*W + dx);  \
      _Pragma("unroll") for(int e=0;e<8;e++) bt[e] = val ? bp[(size_t)e*N] : (unsigned short)0; }

  PREF(0);
  for(int ks = 0; ks < nk; ks++){
    __syncthreads();
    *(short8v*)(As + arow*40 + acol) = av;
    *(short8v*)(Bs + bpx*40 + boct*8) = *(const short8v*)bt;
    __syncthreads();
    if(ks+1 < nk) PREF(ks+1);
    short8v a = *(const short8v*)(As + (wid*16+l15)*40 + 8*g);
    #pragma unroll
    for(int pt=0; pt<4; pt++){
      short8v bf = *(const short8v*)(Bs + (pt*16+l15)*40 + 8*g);
      acc[pt] = __builtin_amdgcn_mfma_f32_16x16x32_bf16(a, bf, acc[pt], 0,0,0);
    }
  }
  #undef PREF
  #pragma unroll
  for(int pt=0; pt<4; pt++){
    #pragma unroll
    for(int r=0; r<4; r++){
      size_t o = ((size_t)b*Cout + co0 + wid*16 + 4*g + r)*N + px0 + pt*16 + l15;
      if(S == 1) out[o] = acc[pt][r];
      else atomicAdd(out + o, acc[pt][r]);
    }
  }
}

// ---------- 1x1 conv at LOW res (up2 commutes with 1x1 conv) ----------
__global__ __launch_bounds__(256) void k_conv1_low(const float* __restrict__ in, fp w, fp bias,
                                                   float* __restrict__ out,
                                                   int Cin, int Cout, int N1){
  int bc = blockIdx.x; int b = bc / Cout; int co = bc % Cout;
  extern __shared__ float ws[];
  for(int i = threadIdx.x; i < Cin; i += blockDim.x) ws[i] = w[(size_t)co*Cin + i];
  __syncthreads();
  const float* inb = in + (size_t)b*Cin*N1;
  float bv = bias[co];
  for(int p = threadIdx.x; p < N1; p += blockDim.x){
    float acc = bv;
    for(int ci = 0; ci < Cin; ci++) acc += inb[(size_t)ci*N1 + p] * ws[ci];
    out[((size_t)b*Cout + co)*N1 + p] = acc;
  }
}

// ---------- concat channels with up2 replication of low-res part ----------
__global__ __launch_bounds__(256) void k_concat_up(const float* __restrict__ a, fp skip,
                                                   float* __restrict__ cat,
                                                   int Ca, int Cs, int N2, int W2){
  int bc = blockIdx.x; int C = Ca + Cs; int b = bc / C; int c = bc % C;
  float* o = cat + (size_t)bc*N2;
  if(c < Ca){
    const float* s = a + ((size_t)b*Ca + c)*(N2/4);
    int W1 = W2/2;
    for(int n = threadIdx.x; n < N2; n += blockDim.x){
      int y = n / W2, x = n % W2;
      o[n] = s[(y>>1)*W1 + (x>>1)];
    }
  }else{
    fp s = skip + ((size_t)b*Cs + (c-Ca))*N2;
    for(int n = threadIdx.x; n < N2; n += blockDim.x) o[n] = s[n];
  }
}

// ---------- tiled transpose [6][C][N] -> [6][N][C] ----------
__global__ __launch_bounds__(256) void k_tr(const float* __restrict__ src, float* __restrict__ dst,
                                            int C, int N){
  __shared__ float t[32][33];
  int b = blockIdx.z;
  int c0 = blockIdx.y*32, n0 = blockIdx.x*32;
  int tx = threadIdx.x & 31, ty = threadIdx.x >> 5;
  for(int i = ty; i < 32; i += 8) t[i][tx] = src[((size_t)b*C + c0+i)*N + n0+tx];
  __syncthreads();
  for(int i = ty; i < 32; i += 8) dst[((size_t)b*N + n0+i)*C + c0+tx] = t[tx][i];
}

// ---------- QKV projection -> bf16 Q (pre-scaled), K, V ----------
__global__ __launch_bounds__(256) void k_projb(const float* __restrict__ xt, fp wq, fp wk, fp wv,
                                               unsigned short* __restrict__ Q,
                                               unsigned short* __restrict__ K,
                                               unsigned short* __restrict__ V, int C, int N){
  int b = blockIdx.y, n = blockIdx.x;
  extern __shared__ float xs[];
  const float* xp = xt + ((size_t)b*N + n)*C;
  for(int c = threadIdx.x; c < C; c += blockDim.x) xs[c] = xp[c];
  __syncthreads();
  float rs = rsqrtf((float)C);
  for(int c = threadIdx.x; c < C; c += blockDim.x){
    float aq = 0.f, ak = 0.f, av = 0.f;
    for(int cc = 0; cc < C; cc++){
      float xv = xs[cc];
      aq += xv * wq[(size_t)cc*C + c];
      ak += xv * wk[(size_t)cc*C + c];
      av += xv * wv[(size_t)cc*C + c];
    }
    size_t o = ((size_t)b*N + n)*C + c;
    Q[o] = f2b(aq*rs); K[o] = f2b(ak); V[o] = f2b(av);
  }
}

// ---------- MFMA flash attention, padded-row LDS (no XOR swizzle) ----------
template<int C>
__global__ __launch_bounds__(256) void k_attn_mfma(const unsigned short* __restrict__ Q,
                                                   const unsigned short* __restrict__ K,
                                                   const unsigned short* __restrict__ V,
                                                   float* __restrict__ ctxn, int N, int j){
  constexpr int KP = C + 8;                // row stride: bank offset 4 per row
  __shared__ unsigned short Ks[32*KP];     // [m][c]
  __shared__ unsigned short Vt[C*40];      // [c][m]
  __shared__ unsigned short ps[4][16*40];  // per-wave P tile [m][k]
  int t = threadIdx.x, wid = t>>6, lane = t&63;
  int l15 = lane&15, g = lane>>4;
  int p = blockIdx.y;
  int q0 = (blockIdx.x*4 + wid)*16;
  const unsigned short* Qb = Q + ((size_t)(p+1)*N + q0)*C;
  const unsigned short* Kb = K + (size_t)(p + (j?2:0))*N*C;
  const unsigned short* Vb = V + (size_t)(p + (j?2:0))*N*C;

  short8v qf[C/32];
  #pragma unroll
  for(int kk = 0; kk < C/32; kk++)
    qf[kk] = *(const short8v*)(Qb + (size_t)l15*C + kk*32 + 8*g);

  f32x4 acc[C/16];
  #pragma unroll
  for(int i = 0; i < C/16; i++) acc[i] = f32x4{0.f,0.f,0.f,0.f};
  float mrow[4] = {-1e30f,-1e30f,-1e30f,-1e30f};
  float lrow[4] = {0.f,0.f,0.f,0.f};

  for(int m0 = 0; m0 < N; m0 += 32){
    __syncthreads();
    for(int idx = t*8; idx < 32*C; idx += 2048){
      int m = idx/C, c = idx - m*C;
      *(short8v*)(Ks + m*KP + c) = *(const short8v*)(Kb + (size_t)(m0+m)*C + c);
    }
    for(int u = t; u < 4*C; u += 256){     // V: one (c, m-oct) per thread
      int oct = u / C, c = u - oct*C;
      unsigned short tmp[8];
      const unsigned short* vp = Vb + (size_t)(m0 + oct*8)*C + c;
      #pragma unroll
      for(int e=0;e<8;e++) tmp[e] = vp[(size_t)e*C];
      *(short8v*)(Vt + c*40 + oct*8) = *(const short8v*)tmp;
    }
    __syncthreads();
    f32x4 s0 = {0.f,0.f,0.f,0.f}, s1 = {0.f,0.f,0.f,0.f};
    #pragma unroll
    for(int kk = 0; kk < C/32; kk++){
      short8v k0 = *(const short8v*)(Ks + l15*KP      + kk*32 + 8*g);
      short8v k1 = *(const short8v*)(Ks + (16+l15)*KP + kk*32 + 8*g);
      s0 = __builtin_amdgcn_mfma_f32_16x16x32_bf16(qf[kk], k0, s0, 0,0,0);
      s1 = __builtin_amdgcn_mfma_f32_16x16x32_bf16(qf[kk], k1, s1, 0,0,0);
    }
    float scl[4];
    #pragma unroll
    for(int r = 0; r < 4; r++){
      float mx = fmaxf(s0[r], s1[r]);
      #pragma unroll
      for(int off = 1; off < 16; off <<= 1) mx = fmaxf(mx, __shfl_xor(mx, off));
      float mnew = fmaxf(mrow[r], mx);
      scl[r] = __expf(mrow[r] - mnew);
      float e0 = __expf(s0[r] - mnew), e1 = __expf(s1[r] - mnew);
      float psum = e0 + e1;
      #pragma unroll
      for(int off = 1; off < 16; off <<= 1) psum += __shfl_xor(psum, off);
      lrow[r] = lrow[r]*scl[r] + psum;
      mrow[r] = mnew;
      int m = 4*g + r;
      ps[wid][m*40 + l15]      = f2b(e0);
      ps[wid][m*40 + 16 + l15] = f2b(e1);
    }
    #pragma unroll
    for(int ct = 0; ct < C/16; ct++){
      #pragma unroll
      for(int r = 0; r < 4; r++) acc[ct][r] *= scl[r];
    }
    short8v pa = *(const short8v*)(ps[wid] + l15*40 + 8*g);
    #pragma unroll
    for(int ct = 0; ct < C/16; ct++){
      short8v vb = *(const short8v*)(Vt + (ct*16+l15)*40 + 8*g);
      acc[ct] = __builtin_amdgcn_mfma_f32_16x16x32_bf16(pa, vb, acc[ct], 0,0,0);
    }
  }
  #pragma unroll
  for(int ct = 0; ct < C/16; ct++){
    int c = ct*16 + l15;
    #pragma unroll
    for(int r = 0; r < 4; r++){
      int m = 4*g + r;
      size_t idx = ((size_t)p*N + q0 + m)*C + c;
      float v = 0.5f*acc[ct][r]/lrow[r];
      if(j) ctxn[idx] += v; else ctxn[idx] = v;
    }
  }
}

// ---------- LayerNorm over C, in place on ctxn rows [4*N][C] ----------
__global__ __launch_bounds__(256) void k_ln(float* __restrict__ ctxn, fp lng, fp lnb, int C){
  __shared__ float r1[4], r2[4];
  float* row = ctxn + (size_t)blockIdx.x*C;
  int t = threadIdx.x;
  float s = 0.f, s2 = 0.f;
  for(int c = t; c < C; c += 256){ float v = row[c]; s += v; s2 += v*v; }
  for(int o = 32; o > 0; o >>= 1){ s += __shfl_down(s, o); s2 += __shfl_down(s2, o); }
  if((t & 63) == 0){ r1[t>>6] = s; r2[t>>6] = s2; }
  __syncthreads();
  if(t == 0){
    float S = r1[0]+r1[1]+r1[2]+r1[3], S2 = r2[0]+r2[1]+r2[2]+r2[3];
    float m = S/(float)C, var = S2/(float)C - m*m;
    r1[0] = m; r2[0] = rsqrtf(var + 1e-5f);
  }
  __syncthreads();
  float m = r1[0], ri = r2[0];
  for(int c = t; c < C; c += 256) row[c] = (row[c] - m)*ri*lng[c] + lnb[c];
}

// ---------- cm[n][c] = mean_p ctxn[p][n][c] ----------
__global__ __launch_bounds__(256) void k_cm(const float* __restrict__ ctxn, float* __restrict__ cm,
                                            int C, int N){
  int n = blockIdx.x;
  for(int c = threadIdx.x; c < C; c += blockDim.x){
    float s = 0.25f*( ctxn[((size_t)0*N + n)*C + c] + ctxn[((size_t)1*N + n)*C + c]
                    + ctxn[((size_t)2*N + n)*C + c] + ctxn[((size_t)3*N + n)*C + c]);
    cm[(size_t)n*C + c] = s;
  }
}

// ---------- h[b][c][n] += cm[n][c] ----------
__global__ __launch_bounds__(256) void k_add(float* __restrict__ h, const float* __restrict__ cm,
                                             int C, int N){
  int bc = blockIdx.x; int c = bc % C;
  float* hp = h + (size_t)bc*N;
  for(int n = threadIdx.x; n < N; n += blockDim.x) hp[n] += cm[(size_t)n*C + c];
}

// ---------- batch-norm stats per channel over (b,n) ----------
__global__ __launch_bounds__(256) void k_bnstat(const float* __restrict__ h, fp bng, fp bnb,
                                                float* __restrict__ ssout, int C, int N){
  __shared__ float red[8], red2[8];
  int c = blockIdx.x; int t = threadIdx.x;
  float s = 0.f, s2 = 0.f;
  for(int b = 0; b < 6; b++){
    const float* hp = h + ((size_t)b*C + c)*N;
    for(int n = t; n < N; n += blockDim.x){ float v = hp[n]; s += v; s2 += v*v; }
  }
  for(int o = 32; o > 0; o >>= 1){ s += __shfl_down(s, o); s2 += __shfl_down(s2, o); }
  int lane = t & 63, wid = t >> 6;
  if(lane == 0){ red[wid] = s; red2[wid] = s2; }
  __syncthreads();
  if(t == 0){
    float S = 0.f, S2 = 0.f; int nw = blockDim.x >> 6;
    for(int i = 0; i < nw; i++){ S += red[i]; S2 += red2[i]; }
    float inv = 1.f/(6.f*(float)N);
    float m = S*inv, var = S2*inv - m*m;
    float sc = bng[c]*rsqrtf(var + 1e-5f);
    ssout[c] = sc; ssout[C + c] = bnb[c] - m*sc;
  }
}

// ---------- BN apply + ReLU, in place ----------
__global__ __launch_bounds__(256) void k_bnrelu(float* __restrict__ h, const float* __restrict__ ssin,
                                                int C, int N){
  int bc = blockIdx.x; int c = bc % C;
  float sc = ssin[c], sh = ssin[C + c];
  float* hp = h + (size_t)bc*N;
  for(int n = threadIdx.x; n < N; n += blockDim.x){
    float v = hp[n]*sc + sh; hp[n] = v > 0.f ? v : 0.f;
  }
}

// ---------- final up2 + f32 store ----------
__global__ __launch_bounds__(256) void k_up_out(const float* __restrict__ in, float* out,
                                                int H, int W){
  int bc = blockIdx.x;
  const float* ip = in + (size_t)bc*H*W;
  float* op = out + (size_t)bc*4*H*W;
  int W2 = 2*W, N2 = 4*H*W;
  for(int p = threadIdx.x; p < N2; p += blockDim.x){
    int y = p / W2, x = p % W2;
    op[p] = ip[(y>>1)*W + (x>>1)];
  }
}

extern "C" void kernel_launch(void* const* d_in, const int* in_sizes, int n_in,
                              void* d_out, int out_size, void* d_ws, size_t ws_size,
                              hipStream_t stream){
  float* out_f = (float*)d_out;
  static const int EXP[36] = {294912,393216,786432,1572864,3538944,512,
    131072,256,262144,262144,262144,512,512,512,512,1179648,
    32768,128,65536,65536,65536,256,256,256,256,294912,
    8192,64,16384,16384,16384,128,128,128,128,73728};
  bool ok = (n_in == 36) && (out_size == 6291456);
  if(ok) for(int i = 0; i < 36; i++) if(in_sizes[i] != EXP[i]){ ok = false; break; }
  if(!ok){
    k_fill<<<(out_size+255)/256, 256, 0, stream>>>(out_f, out_size, 10.0f);
    return;
  }
  const size_t R = 3145728;
  const size_t NEED = (5*R + 1024)*sizeof(float);
  if(ws_size < NEED){
    k_fill<<<(out_size+255)/256, 256, 0, stream>>>(out_f, out_size, 100.0f);
    return;
  }
  (void)hipGetLastError();
  #define CKERR(code) do{ if(hipGetLastError() != hipSuccess){ \
      k_fill<<<(out_size+255)/256, 256, 0, stream>>>(out_f, out_size, (float)(code)); \
      return; } }while(0)

  fp x = (fp)d_in[0];
  fp skip[3]  = {(fp)d_in[1],(fp)d_in[2],(fp)d_in[3]};
  fp w_sc = (fp)d_in[4], b_sc = (fp)d_in[5];
  fp w_up[3] = {(fp)d_in[6], (fp)d_in[16],(fp)d_in[26]};
  fp b_up[3] = {(fp)d_in[7], (fp)d_in[17],(fp)d_in[27]};
  fp wq[3]   = {(fp)d_in[8], (fp)d_in[18],(fp)d_in[28]};
  fp wk[3]   = {(fp)d_in[9], (fp)d_in[19],(fp)d_in[29]};
  fp wv[3]   = {(fp)d_in[10],(fp)d_in[20],(fp)d_in[30]};
  fp lng[3]  = {(fp)d_in[11],(fp)d_in[21],(fp)d_in[31]};
  fp lnb[3]  = {(fp)d_in[12],(fp)d_in[22],(fp)d_in[32]};
  fp bng[3]  = {(fp)d_in[13],(fp)d_in[23],(fp)d_in[33]};
  fp bnb[3]  = {(fp)d_in[14],(fp)d_in[24],(fp)d_in[34]};
  fp w_cb[3] = {(fp)d_in[15],(fp)d_in[25],(fp)d_in[35]};

  float* Wp = (float*)d_ws;
  float *Cc = Wp, *XT = Wp + R;
  unsigned short *QB = (unsigned short*)(Wp + 2*R),
                 *KB = (unsigned short*)(Wp + 3*R),
                 *VB = (unsigned short*)(Wp + 4*R);
  float *SS = Wp + 5*R;
  float *CT = XT, *OB = XT, *Bf = Wp + 2*R, *CM = Wp + 2*R;  // aliases (liveness-verified)
  unsigned short *WT = KB, *IB = VB;   // conv weight/input bf16 (K,V dead at conv time)

  // stage 0: x -> h0 (Cc); bf16 input+weights; bias prefill; split-K conv -> OB [6,512,8,8]
  k_in_tr<<<dim3(64,6),256,0,stream>>>(x, Cc);
  k_b16<<<(294912/8+255)/256, 256, 0, stream>>>(Cc, IB, 294912);
  k_wtr<<<(9*512*768+255)/256, 256, 0, stream>>>(w_sc, WT, 512, 768);
  k_fillb<<<(6*512*64+255)/256, 256, 0, stream>>>(OB, b_sc, 512, 64);
  k_conv3_mfma2<<<dim3(1,8,6*8), 256, 0, stream>>>(WT, IB, OB, 768, 512, 8, 8, 8);
  CKERR(20);

  const int Cskip[3] = {256,128,64};
  const int Hs[3]    = {16,32,64};
  const int SPL[3]   = {4,2,1};
  int Cprev = 512;
  for(int i = 0; i < 3; i++){
    int H = Hs[i], N = H*H;
    int N1 = N/4;
    int Cup = Cprev/2;
    int C = Cup + Cskip[i];
    k_conv1_low<<<6*Cup, 256, Cprev*4, stream>>>(OB, w_up[i], b_up[i], Bf, Cprev, Cup, N1);
    k_concat_up<<<6*C, 256, 0, stream>>>(Bf, skip[i], Cc, Cup, Cskip[i], N, H);
    k_tr<<<dim3(N/32, C/32, 6), 256, 0, stream>>>(Cc, XT, C, N);
    k_projb<<<dim3(N,6), 256, C*4, stream>>>(XT, wq[i], wk[i], wv[i], QB, KB, VB, C, N);
    CKERR(30 + 10*i);
    for(int j = 0; j < 2; j++){
      if(i==0) k_attn_mfma<512><<<dim3(N/64,4),256,0,stream>>>(QB,KB,VB,CT,N,j);
      if(i==1) k_attn_mfma<256><<<dim3(N/64,4),256,0,stream>>>(QB,KB,VB,CT,N,j);
      if(i==2) k_attn_mfma<128><<<dim3(N/64,4),256,0,stream>>>(QB,KB,VB,CT,N,j);
    }
    k_ln<<<4*N, 256, 0, stream>>>(CT, lng[i], lnb[i], C);
    CKERR(32 + 10*i);
    k_cm<<<N, 256, 0, stream>>>(CT, CM, C, N);
    k_add<<<6*C, 256, 0, stream>>>(Cc, CM, C, N);
    k_bnstat<<<C, 256, 0, stream>>>(Cc, bng[i], bnb[i], SS, C, N);
    k_bnrelu<<<6*C, 256, 0, stream>>>(Cc, SS, C, N);
    // cb conv: bf16 transform (K,V regions dead now) + split-K MFMA conv
    int Co = C/2, S = SPL[i];
    k_b16<<<(6*C*N/8+255)/256, 256, 0, stream>>>(Cc, IB, 6*C*N);
    k_wtr<<<(9*Co*C+255)/256, 256, 0, stream>>>(w_cb[i], WT, Co, C);
    if(S > 1) k_fill<<<(6*Co*N+255)/256, 256, 0, stream>>>(OB, 6*Co*N, 0.f);
    k_conv3_mfma2<<<dim3(N/64, Co/64, 6*S), 256, 0, stream>>>(WT, IB, OB, C, Co, H, H, S);
    CKERR(34 + 10*i);
    Cprev = Co;
  }
  k_up_out<<<6*64, 256, 0, stream>>>(OB, out_f, 64, 64);
  CKERR(90);
  #undef CKERR
}

// Round 9
// 1140.811 us; speedup vs baseline: 9.9360x; 1.6128x over previous
//
#include <hip/hip_runtime.h>
#include <hip/hip_bf16.h>

typedef const float* fp;
typedef unsigned short u16;
typedef __attribute__((ext_vector_type(8))) short short8v;   // 8 bf16 (4 VGPR)
typedef __attribute__((ext_vector_type(4))) float f32x4;

__device__ __forceinline__ u16 f2b(float f){       // f32 -> bf16 RNE
  union{float f; unsigned u;} x; x.f = f;
  unsigned r = x.u + 0x7FFFu + ((x.u>>16)&1u);
  return (u16)(r>>16);
}

// ---------- sentinel fill ----------
__global__ __launch_bounds__(256) void k_fill(float* out, int n, float v){
  int i = blockIdx.x*256 + threadIdx.x;
  if(i < n) out[i] = v;
}
// ---------- per-channel bias fill ----------
__global__ __launch_bounds__(256) void k_fillb(float* out, fp bias, int Cout, int N){
  int i = blockIdx.x*256 + threadIdx.x;
  if(i < 6*Cout*N) out[i] = bias[(i/N)%Cout];
}
// ---------- f32 -> bf16 elementwise ----------
__global__ __launch_bounds__(256) void k_b16(fp in, u16* o, int n){
  int i = (blockIdx.x*256 + threadIdx.x)*8;
  if(i >= n) return;
  u16 tmp[8];
  #pragma unroll
  for(int e=0;e<8;e++) tmp[e] = f2b(in[i+e]);
  *(short8v*)(o+i) = *(const short8v*)tmp;
}
// ---------- conv weight transform: w[Cout][Cin][9] f32 -> wt[9][Cout][Cin] bf16 ----------
__global__ __launch_bounds__(256) void k_wtr(fp w, u16* wt, int Cout, int Cin){
  int idx = blockIdx.x*256 + threadIdx.x;
  int cc = Cout*Cin;
  if(idx >= 9*cc) return;
  int tap = idx / cc, rem = idx - tap*cc;
  wt[idx] = f2b(w[(size_t)rem*9 + tap]);
}
// ---------- qkv weight transform: {wq,wk,wv}[Cin][Cout] -> BT[3C][C] bf16 (Q rows scaled) ----------
__global__ __launch_bounds__(256) void k_wqkvt(fp wq, fp wk, fp wv, u16* bt, int C, float rs){
  int idx = blockIdx.x*256 + threadIdx.x;
  if(idx >= 3*C*C) return;
  int r = idx / C, ci = idx - r*C;
  int sel = r / C, co = r - sel*C;
  float v = (sel==0 ? wq : sel==1 ? wk : wv)[(size_t)ci*C + co];
  bt[idx] = f2b(sel==0 ? v*rs : v);
}

// ---------- input transpose: x [6,64,768] f32 -> h0 [6,768,64] f32 ----------
__global__ __launch_bounds__(256) void k_in_tr(fp x, float* h0){
  int n = blockIdx.x, b = blockIdx.y;
  for(int d = threadIdx.x; d < 768; d += blockDim.x)
    h0[((size_t)b*768 + d)*64 + n] = x[((size_t)b*64 + n)*768 + d];
}

// ---------- tap-decomposed implicit-GEMM MFMA 3x3 conv, split-K ----------
__global__ __launch_bounds__(256) void k_conv3_mfma2(const u16* __restrict__ wt,
    const u16* __restrict__ inb16, float* __restrict__ out,
    int Cin, int Cout, int H, int W, int S){
  const int N = H*W;
  __shared__ u16 As[64*40];
  __shared__ u16 Bs[64*40];
  int t = threadIdx.x, wid = t>>6, lane = t&63, l15 = lane&15, g = lane>>4;
  int b = blockIdx.z / S, s = blockIdx.z % S;
  int co0 = blockIdx.y*64, px0 = blockIdx.x*64;
  int ciN = Cin/S, ci0 = s*ciN;
  const u16* inb = inb16 + (size_t)b*Cin*N;
  int arow = t>>2, acol = (t&3)*8;
  int bpx = t&63, boct = t>>6;
  int p = px0 + bpx, py = p/W, px_ = p - py*W;
  int nc = ciN >> 5, nk = 9*nc;
  f32x4 acc[4];
  #pragma unroll
  for(int i=0;i<4;i++) acc[i] = f32x4{0.f,0.f,0.f,0.f};
  short8v av; u16 bt[8];

  #define PREF(ks) { int tap = (ks)/nc; int c0 = ((ks) - tap*nc)<<5;                     \
      int dy = tap/3 - 1, dx = tap - (tap/3)*3 - 1;                                      \
      av = *(const short8v*)(wt + ((size_t)tap*Cout + co0 + arow)*Cin + ci0 + c0 + acol);\
      bool val = ((unsigned)(py+dy) < (unsigned)H) && ((unsigned)(px_+dx) < (unsigned)W);\
      const u16* bp = inb + (size_t)(ci0 + c0 + boct*8)*N + (p + dy*W + dx);             \
      _Pragma("unroll") for(int e=0;e<8;e++) bt[e] = val ? bp[(size_t)e*N] : (u16)0; }

  PREF(0);
  for(int ks = 0; ks < nk; ks++){
    __syncthreads();
    *(short8v*)(As + arow*40 + acol) = av;
    *(short8v*)(Bs + bpx*40 + boct*8) = *(const short8v*)bt;
    __syncthreads();
    if(ks+1 < nk) PREF(ks+1);
    short8v a = *(const short8v*)(As + (wid*16+l15)*40 + 8*g);
    #pragma unroll
    for(int pt=0; pt<4; pt++){
      short8v bf = *(const short8v*)(Bs + (pt*16+l15)*40 + 8*g);
      acc[pt] = __builtin_amdgcn_mfma_f32_16x16x32_bf16(a, bf, acc[pt], 0,0,0);
    }
  }
  #undef PREF
  #pragma unroll
  for(int pt=0; pt<4; pt++){
    #pragma unroll
    for(int r=0; r<4; r++){
      size_t o = ((size_t)b*Cout + co0 + wid*16 + 4*g + r)*N + px0 + pt*16 + l15;
      if(S == 1) out[o] = acc[pt][r];
      else atomicAdd(out + o, acc[pt][r]);
    }
  }
}

// ---------- QKV projection GEMM: XB[6N][C] @ BT[3C][C]^T -> Q,K,V bf16 ----------
__global__ __launch_bounds__(256) void k_gemm_qkv(const u16* __restrict__ XB,
    const u16* __restrict__ BT, u16* __restrict__ Qo, u16* __restrict__ Ko,
    u16* __restrict__ Vo, int C){
  __shared__ u16 As[64*40], Bs[64*40];
  int t = threadIdx.x, wid = t>>6, lane = t&63, l15 = lane&15, g = lane>>4;
  int r0 = blockIdx.x*64, c0 = blockIdx.y*64;
  int arow = t>>2, acol = (t&3)*8;
  int nk = C/32;
  f32x4 acc[4];
  #pragma unroll
  for(int i=0;i<4;i++) acc[i] = f32x4{0.f,0.f,0.f,0.f};
  short8v av = *(const short8v*)(XB + (size_t)(r0+arow)*C + acol);
  short8v bv = *(const short8v*)(BT + (size_t)(c0+arow)*C + acol);
  for(int ks = 0; ks < nk; ks++){
    __syncthreads();
    *(short8v*)(As + arow*40 + acol) = av;
    *(short8v*)(Bs + arow*40 + acol) = bv;
    __syncthreads();
    if(ks+1 < nk){
      int k0 = (ks+1)*32;
      av = *(const short8v*)(XB + (size_t)(r0+arow)*C + k0 + acol);
      bv = *(const short8v*)(BT + (size_t)(c0+arow)*C + k0 + acol);
    }
    short8v a = *(const short8v*)(As + (wid*16+l15)*40 + 8*g);
    #pragma unroll
    for(int pt=0; pt<4; pt++){
      short8v bf = *(const short8v*)(Bs + (pt*16+l15)*40 + 8*g);
      acc[pt] = __builtin_amdgcn_mfma_f32_16x16x32_bf16(a, bf, acc[pt], 0,0,0);
    }
  }
  int sel = c0 / C, cb = c0 - sel*C;
  u16* ob = sel==0 ? Qo : (sel==1 ? Ko : Vo);
  #pragma unroll
  for(int pt=0; pt<4; pt++){
    #pragma unroll
    for(int r=0; r<4; r++)
      ob[(size_t)(r0 + wid*16 + 4*g + r)*C + cb + pt*16 + l15] = f2b(acc[pt][r]);
  }
}

// ---------- 1x1 conv at LOW res ----------
__global__ void k_conv1_low(const float* __restrict__ in, fp w, fp bias,
                            float* __restrict__ out, int Cin, int Cout, int N1){
  int bc = blockIdx.x; int b = bc / Cout; int co = bc % Cout;
  extern __shared__ float ws[];
  for(int i = threadIdx.x; i < Cin; i += blockDim.x) ws[i] = w[(size_t)co*Cin + i];
  __syncthreads();
  const float* inb = in + (size_t)b*Cin*N1;
  float bv = bias[co];
  for(int p = threadIdx.x; p < N1; p += blockDim.x){
    float acc = bv;
    for(int ci = 0; ci < Cin; ci++) acc += inb[(size_t)ci*N1 + p] * ws[ci];
    out[((size_t)b*Cout + co)*N1 + p] = acc;
  }
}

// ---------- concat channels with up2 replication of low-res part ----------
__global__ __launch_bounds__(256) void k_concat_up(const float* __restrict__ a, fp skip,
                                                   float* __restrict__ cat,
                                                   int Ca, int Cs, int N2, int W2){
  int bc = blockIdx.x; int C = Ca + Cs; int b = bc / C; int c = bc % C;
  float* o = cat + (size_t)bc*N2;
  if(c < Ca){
    const float* s = a + ((size_t)b*Ca + c)*(N2/4);
    int W1 = W2/2;
    for(int n = threadIdx.x; n < N2; n += blockDim.x){
      int y = n / W2, x = n % W2;
      o[n] = s[(y>>1)*W1 + (x>>1)];
    }
  }else{
    fp s = skip + ((size_t)b*Cs + (c-Ca))*N2;
    for(int n = threadIdx.x; n < N2; n += blockDim.x) o[n] = s[n];
  }
}

// ---------- tiled transpose+bf16: [6][C][N] f32 -> [6][N][C] bf16 ----------
__global__ __launch_bounds__(256) void k_trb(const float* __restrict__ src, u16* __restrict__ dst,
                                             int C, int N){
  __shared__ float tb[32][33];
  int b = blockIdx.z;
  int c0 = blockIdx.y*32, n0 = blockIdx.x*32;
  int tx = threadIdx.x & 31, ty = threadIdx.x >> 5;
  for(int i = ty; i < 32; i += 8) tb[i][tx] = src[((size_t)b*C + c0+i)*N + n0+tx];
  __syncthreads();
  for(int i = ty; i < 32; i += 8) dst[((size_t)b*N + n0+i)*C + c0+tx] = f2b(tb[tx][i]);
}

// ---------- MFMA flash attention C=128: KVB=64, j-merged, prefetch, defer-max ----------
__global__ __launch_bounds__(256) void k_attn128(const u16* __restrict__ Q,
                                                 const u16* __restrict__ K,
                                                 const u16* __restrict__ V,
                                                 float* __restrict__ ctxn, int N){
  constexpr int C = 128, KVB = 64, KP = C+8, VP = KVB+8;
  __shared__ u16 Ks[KVB*KP];
  __shared__ u16 Vt[C*VP];
  __shared__ u16 ps[4][16*VP];
  int t = threadIdx.x, wid = t>>6, lane = t&63, l15 = lane&15, g = lane>>4;
  int p = blockIdx.y, q0 = (blockIdx.x*4 + wid)*16;
  const u16* Qb = Q + ((size_t)(p+1)*N + q0)*C;
  short8v qf[4];
  #pragma unroll
  for(int kk = 0; kk < 4; kk++)
    qf[kk] = *(const short8v*)(Qb + (size_t)l15*C + kk*32 + 8*g);
  f32x4 ctx[8];
  #pragma unroll
  for(int i=0;i<8;i++) ctx[i] = f32x4{0.f,0.f,0.f,0.f};

  #define APREF(M0) { _Pragma("unroll") for(int i=0;i<4;i++){                     \
        int idx = t*8 + i*2048; int mm = idx>>7, cc = idx&127;                    \
        kpre[i] = *(const short8v*)(Kb + (size_t)((M0)+mm)*C + cc); }             \
      _Pragma("unroll") for(int u=0;u<4;u++){                                     \
        int uu = t + u*256; int oct = uu>>7, cc = uu&127;                         \
        const u16* vp = Vb + (size_t)((M0)+oct*8)*C + cc;                         \
        _Pragma("unroll") for(int e=0;e<4;e++){                                   \
          unsigned lo = vp[(size_t)(2*e)*C], hi = vp[(size_t)(2*e+1)*C];          \
          vpre[u][e] = lo | (hi<<16); } } }

  for(int j = 0; j < 2; j++){
    const u16* Kb = K + (size_t)(p + (j?2:0))*N*C;
    const u16* Vb = V + (size_t)(p + (j?2:0))*N*C;
    f32x4 acc[8];
    #pragma unroll
    for(int i=0;i<8;i++) acc[i] = f32x4{0.f,0.f,0.f,0.f};
    float m[4] = {-1e30f,-1e30f,-1e30f,-1e30f};
    float l[4] = {0.f,0.f,0.f,0.f};
    short8v kpre[4]; unsigned vpre[4][4];
    APREF(0);
    for(int m0 = 0; m0 < N; m0 += KVB){
      __syncthreads();
      #pragma unroll
      for(int i=0;i<4;i++){ int idx = t*8 + i*2048; int mm = idx>>7, cc = idx&127;
        *(short8v*)(Ks + mm*KP + cc) = kpre[i]; }
      #pragma unroll
      for(int u=0;u<4;u++){ int uu = t + u*256; int oct = uu>>7, cc = uu&127;
        *(short8v*)(Vt + cc*VP + oct*8) = *(const short8v*)&vpre[u][0]; }
      __syncthreads();
      if(m0 + KVB < N) APREF(m0 + KVB);
      f32x4 s[4];
      #pragma unroll
      for(int h=0; h<4; h++){
        s[h] = f32x4{0.f,0.f,0.f,0.f};
        #pragma unroll
        for(int kk=0; kk<4; kk++){
          short8v kf = *(const short8v*)(Ks + (h*16+l15)*KP + kk*32 + 8*g);
          s[h] = __builtin_amdgcn_mfma_f32_16x16x32_bf16(qf[kk], kf, s[h], 0,0,0);
        }
      }
      float pmax[4]; bool need = false;
      #pragma unroll
      for(int r=0; r<4; r++){
        float mx = fmaxf(fmaxf(s[0][r],s[1][r]), fmaxf(s[2][r],s[3][r]));
        #pragma unroll
        for(int off=1; off<16; off<<=1) mx = fmaxf(mx, __shfl_xor(mx, off));
        pmax[r] = mx; need |= (mx > m[r] + 8.f);
      }
      if(__any((int)need)){
        #pragma unroll
        for(int r=0; r<4; r++){
          float mnew = fmaxf(m[r], pmax[r]);
          float scl = __expf(m[r] - mnew);
          l[r] *= scl; m[r] = mnew;
          #pragma unroll
          for(int ct=0; ct<8; ct++) acc[ct][r] *= scl;
        }
      }
      #pragma unroll
      for(int r=0; r<4; r++){
        float psum = 0.f;
        #pragma unroll
        for(int h=0; h<4; h++){
          float e = __expf(s[h][r] - m[r]); psum += e;
          ps[wid][(4*g+r)*VP + h*16 + l15] = f2b(e);
        }
        #pragma unroll
        for(int off=1; off<16; off<<=1) psum += __shfl_xor(psum, off);
        l[r] += psum;
      }
      #pragma unroll
      for(int ks=0; ks<2; ks++){
        short8v pa = *(const short8v*)(ps[wid] + l15*VP + ks*32 + 8*g);
        #pragma unroll
        for(int ct=0; ct<8; ct++){
          short8v vb = *(const short8v*)(Vt + (ct*16+l15)*VP + ks*32 + 8*g);
          acc[ct] = __builtin_amdgcn_mfma_f32_16x16x32_bf16(pa, vb, acc[ct], 0,0,0);
        }
      }
    }
    #pragma unroll
    for(int r=0; r<4; r++){
      float inv = 0.5f/l[r];
      #pragma unroll
      for(int ct=0; ct<8; ct++) ctx[ct][r] += acc[ct][r]*inv;
    }
  }
  #undef APREF
  #pragma unroll
  for(int ct=0; ct<8; ct++){
    int c = ct*16 + l15;
    #pragma unroll
    for(int r=0; r<4; r++)
      ctxn[((size_t)p*N + q0 + 4*g + r)*C + c] = ctx[ct][r];
  }
}

// ---------- MFMA flash attention (C=256/512), per-j launch (r8-proven) ----------
template<int C>
__global__ __launch_bounds__(256) void k_attn_mfma(const u16* __restrict__ Q,
                                                   const u16* __restrict__ K,
                                                   const u16* __restrict__ V,
                                                   float* __restrict__ ctxn, int N, int j){
  constexpr int KP = C + 8;
  __shared__ u16 Ks[32*KP];
  __shared__ u16 Vt[C*40];
  __shared__ u16 ps[4][16*40];
  int t = threadIdx.x, wid = t>>6, lane = t&63;
  int l15 = lane&15, g = lane>>4;
  int p = blockIdx.y;
  int q0 = (blockIdx.x*4 + wid)*16;
  const u16* Qb = Q + ((size_t)(p+1)*N + q0)*C;
  const u16* Kb = K + (size_t)(p + (j?2:0))*N*C;
  const u16* Vb = V + (size_t)(p + (j?2:0))*N*C;

  short8v qf[C/32];
  #pragma unroll
  for(int kk = 0; kk < C/32; kk++)
    qf[kk] = *(const short8v*)(Qb + (size_t)l15*C + kk*32 + 8*g);

  f32x4 acc[C/16];
  #pragma unroll
  for(int i = 0; i < C/16; i++) acc[i] = f32x4{0.f,0.f,0.f,0.f};
  float mrow[4] = {-1e30f,-1e30f,-1e30f,-1e30f};
  float lrow[4] = {0.f,0.f,0.f,0.f};

  for(int m0 = 0; m0 < N; m0 += 32){
    __syncthreads();
    for(int idx = t*8; idx < 32*C; idx += 2048){
      int m = idx/C, c = idx - m*C;
      *(short8v*)(Ks + m*KP + c) = *(const short8v*)(Kb + (size_t)(m0+m)*C + c);
    }
    for(int u = t; u < 4*C; u += 256){
      int oct = u / C, c = u - oct*C;
      u16 tmp[8];
      const u16* vp = Vb + (size_t)(m0 + oct*8)*C + c;
      #pragma unroll
      for(int e=0;e<8;e++) tmp[e] = vp[(size_t)e*C];
      *(short8v*)(Vt + c*40 + oct*8) = *(const short8v*)tmp;
    }
    __syncthreads();
    f32x4 s0 = {0.f,0.f,0.f,0.f}, s1 = {0.f,0.f,0.f,0.f};
    #pragma unroll
    for(int kk = 0; kk < C/32; kk++){
      short8v k0 = *(const short8v*)(Ks + l15*KP      + kk*32 + 8*g);
      short8v k1 = *(const short8v*)(Ks + (16+l15)*KP + kk*32 + 8*g);
      s0 = __builtin_amdgcn_mfma_f32_16x16x32_bf16(qf[kk], k0, s0, 0,0,0);
      s1 = __builtin_amdgcn_mfma_f32_16x16x32_bf16(qf[kk], k1, s1, 0,0,0);
    }
    float scl[4];
    #pragma unroll
    for(int r = 0; r < 4; r++){
      float mx = fmaxf(s0[r], s1[r]);
      #pragma unroll
      for(int off = 1; off < 16; off <<= 1) mx = fmaxf(mx, __shfl_xor(mx, off));
      float mnew = fmaxf(mrow[r], mx);
      scl[r] = __expf(mrow[r] - mnew);
      float e0 = __expf(s0[r] - mnew), e1 = __expf(s1[r] - mnew);
      float psum = e0 + e1;
      #pragma unroll
      for(int off = 1; off < 16; off <<= 1) psum += __shfl_xor(psum, off);
      lrow[r] = lrow[r]*scl[r] + psum;
      mrow[r] = mnew;
      int m = 4*g + r;
      ps[wid][m*40 + l15]      = f2b(e0);
      ps[wid][m*40 + 16 + l15] = f2b(e1);
    }
    #pragma unroll
    for(int ct = 0; ct < C/16; ct++){
      #pragma unroll
      for(int r = 0; r < 4; r++) acc[ct][r] *= scl[r];
    }
    short8v pa = *(const short8v*)(ps[wid] + l15*40 + 8*g);
    #pragma unroll
    for(int ct = 0; ct < C/16; ct++){
      short8v vb = *(const short8v*)(Vt + (ct*16+l15)*40 + 8*g);
      acc[ct] = __builtin_amdgcn_mfma_f32_16x16x32_bf16(pa, vb, acc[ct], 0,0,0);
    }
  }
  #pragma unroll
  for(int ct = 0; ct < C/16; ct++){
    int c = ct*16 + l15;
    #pragma unroll
    for(int r = 0; r < 4; r++){
      int m = 4*g + r;
      size_t idx = ((size_t)p*N + q0 + m)*C + c;
      float v = 0.5f*acc[ct][r]/lrow[r];
      if(j) ctxn[idx] += v; else ctxn[idx] = v;
    }
  }
}

// ---------- LayerNorm over C, wave-only, in place on ctxn rows [4*N][C] ----------
__global__ __launch_bounds__(64) void k_ln64(float* __restrict__ ctxn, fp lng, fp lnb, int C){
  float* row = ctxn + (size_t)blockIdx.x*C;
  int t = threadIdx.x;
  float s = 0.f, s2 = 0.f;
  for(int c = t; c < C; c += 64){ float v = row[c]; s += v; s2 += v*v; }
  #pragma unroll
  for(int off = 32; off > 0; off >>= 1){ s += __shfl_xor(s, off); s2 += __shfl_xor(s2, off); }
  float m = s/(float)C, var = s2/(float)C - m*m;
  float ri = rsqrtf(var + 1e-5f);
  for(int c = t; c < C; c += 64) row[c] = (row[c] - m)*ri*lng[c] + lnb[c];
}

// ---------- cm[n][c] = mean_p ctxn[p][n][c] ----------
__global__ void k_cm(const float* __restrict__ ctxn, float* __restrict__ cm, int C, int N){
  int n = blockIdx.x;
  for(int c = threadIdx.x; c < C; c += blockDim.x){
    float s = 0.25f*( ctxn[((size_t)0*N + n)*C + c] + ctxn[((size_t)1*N + n)*C + c]
                    + ctxn[((size_t)2*N + n)*C + c] + ctxn[((size_t)3*N + n)*C + c]);
    cm[(size_t)n*C + c] = s;
  }
}

// ---------- h[b][c][n] += cm[n][c] ----------
__global__ __launch_bounds__(256) void k_add(float* __restrict__ h, const float* __restrict__ cm,
                                             int C, int N){
  int bc = blockIdx.x; int c = bc % C;
  float* hp = h + (size_t)bc*N;
  for(int n = threadIdx.x; n < N; n += blockDim.x) hp[n] += cm[(size_t)n*C + c];
}

// ---------- batch-norm stats per channel over (b,n) ----------
__global__ __launch_bounds__(256) void k_bnstat(const float* __restrict__ h, fp bng, fp bnb,
                                                float* __restrict__ ssout, int C, int N){
  __shared__ float red[8], red2[8];
  int c = blockIdx.x; int t = threadIdx.x;
  float s = 0.f, s2 = 0.f;
  for(int b = 0; b < 6; b++){
    const float* hp = h + ((size_t)b*C + c)*N;
    for(int n = t; n < N; n += blockDim.x){ float v = hp[n]; s += v; s2 += v*v; }
  }
  for(int o = 32; o > 0; o >>= 1){ s += __shfl_down(s, o); s2 += __shfl_down(s2, o); }
  int lane = t & 63, wid = t >> 6;
  if(lane == 0){ red[wid] = s; red2[wid] = s2; }
  __syncthreads();
  if(t == 0){
    float S = 0.f, S2 = 0.f; int nw = blockDim.x >> 6;
    for(int i = 0; i < nw; i++){ S += red[i]; S2 += red2[i]; }
    float inv = 1.f/(6.f*(float)N);
    float m = S*inv, var = S2*inv - m*m;
    float sc = bng[c]*rsqrtf(var + 1e-5f);
    ssout[c] = sc; ssout[C + c] = bnb[c] - m*sc;
  }
}

// ---------- BN apply + ReLU, in place ----------
__global__ __launch_bounds__(256) void k_bnrelu(float* __restrict__ h, const float* __restrict__ ssin,
                                                int C, int N){
  int bc = blockIdx.x; int c = bc % C;
  float sc = ssin[c], sh = ssin[C + c];
  float* hp = h + (size_t)bc*N;
  for(int n = threadIdx.x; n < N; n += blockDim.x){
    float v = hp[n]*sc + sh; hp[n] = v > 0.f ? v : 0.f;
  }
}

// ---------- final up2 + f32 store ----------
__global__ __launch_bounds__(256) void k_up_out(const float* __restrict__ in, float* out,
                                                int H, int W){
  int bc = blockIdx.x;
  const float* ip = in + (size_t)bc*H*W;
  float* op = out + (size_t)bc*4*H*W;
  int W2 = 2*W, N2 = 4*H*W;
  for(int p = threadIdx.x; p < N2; p += blockDim.x){
    int y = p / W2, x = p % W2;
    op[p] = ip[(y>>1)*W + (x>>1)];
  }
}

extern "C" void kernel_launch(void* const* d_in, const int* in_sizes, int n_in,
                              void* d_out, int out_size, void* d_ws, size_t ws_size,
                              hipStream_t stream){
  float* out_f = (float*)d_out;
  static const int EXP[36] = {294912,393216,786432,1572864,3538944,512,
    131072,256,262144,262144,262144,512,512,512,512,1179648,
    32768,128,65536,65536,65536,256,256,256,256,294912,
    8192,64,16384,16384,16384,128,128,128,128,73728};
  bool ok = (n_in == 36) && (out_size == 6291456);
  if(ok) for(int i = 0; i < 36; i++) if(in_sizes[i] != EXP[i]){ ok = false; break; }
  if(!ok){
    k_fill<<<(out_size+255)/256, 256, 0, stream>>>(out_f, out_size, 10.0f);
    return;
  }
  const size_t R = 3145728;
  const size_t NEED = (5*R + 1024)*sizeof(float);
  if(ws_size < NEED){
    k_fill<<<(out_size+255)/256, 256, 0, stream>>>(out_f, out_size, 100.0f);
    return;
  }
  (void)hipGetLastError();
  #define CKERR(code) do{ if(hipGetLastError() != hipSuccess){ \
      k_fill<<<(out_size+255)/256, 256, 0, stream>>>(out_f, out_size, (float)(code)); \
      return; } }while(0)

  fp x = (fp)d_in[0];
  fp skip[3]  = {(fp)d_in[1],(fp)d_in[2],(fp)d_in[3]};
  fp w_sc = (fp)d_in[4], b_sc = (fp)d_in[5];
  fp w_up[3] = {(fp)d_in[6], (fp)d_in[16],(fp)d_in[26]};
  fp b_up[3] = {(fp)d_in[7], (fp)d_in[17],(fp)d_in[27]};
  fp wq[3]   = {(fp)d_in[8], (fp)d_in[18],(fp)d_in[28]};
  fp wk[3]   = {(fp)d_in[9], (fp)d_in[19],(fp)d_in[29]};
  fp wv[3]   = {(fp)d_in[10],(fp)d_in[20],(fp)d_in[30]};
  fp lng[3]  = {(fp)d_in[11],(fp)d_in[21],(fp)d_in[31]};
  fp lnb[3]  = {(fp)d_in[12],(fp)d_in[22],(fp)d_in[32]};
  fp bng[3]  = {(fp)d_in[13],(fp)d_in[23],(fp)d_in[33]};
  fp bnb[3]  = {(fp)d_in[14],(fp)d_in[24],(fp)d_in[34]};
  fp w_cb[3] = {(fp)d_in[15],(fp)d_in[25],(fp)d_in[35]};

  float* Wp = (float*)d_ws;
  float *Cc = Wp, *CT = Wp + R;
  u16 *QB = (u16*)(Wp + 2*R), *KB = (u16*)(Wp + 3*R), *VB = (u16*)(Wp + 4*R);
  float *SS = Wp + 5*R;
  float *OB = Wp + R, *Bf = Wp + 2*R, *CM = Wp + 2*R;   // aliases (liveness-verified)
  u16 *XB  = QB + R;        // QB region upper half (R floats = 2R ushorts)
  u16 *WQT = KB + R;        // KB region upper half
  u16 *WT = KB, *IB = VB;   // conv weight/input bf16 (K,V dead at conv time)

  // stage 0
  k_in_tr<<<dim3(64,6),256,0,stream>>>(x, Cc);
  k_b16<<<(294912/8+255)/256, 256, 0, stream>>>(Cc, IB, 294912);
  k_wtr<<<(9*512*768+255)/256, 256, 0, stream>>>(w_sc, WT, 512, 768);
  k_fillb<<<(6*512*64+255)/256, 256, 0, stream>>>(OB, b_sc, 512, 64);
  k_conv3_mfma2<<<dim3(1,8,6*8), 256, 0, stream>>>(WT, IB, OB, 768, 512, 8, 8, 8);
  CKERR(20);

  const int Cskip[3] = {256,128,64};
  const int Hs[3]    = {16,32,64};
  const int SPL[3]   = {4,2,1};
  int Cprev = 512;
  for(int i = 0; i < 3; i++){
    int H = Hs[i], N = H*H;
    int N1 = N/4;
    int Cup = Cprev/2;
    int C = Cup + Cskip[i];
    k_conv1_low<<<6*Cup, (N1<256?N1:256), Cprev*4, stream>>>(OB, w_up[i], b_up[i], Bf, Cprev, Cup, N1);
    k_concat_up<<<6*C, 256, 0, stream>>>(Bf, skip[i], Cc, Cup, Cskip[i], N, H);
    k_trb<<<dim3(N/32, C/32, 6), 256, 0, stream>>>(Cc, XB, C, N);
    float rsv = 1.f/sqrtf((float)C);
    k_wqkvt<<<(3*C*C+255)/256, 256, 0, stream>>>(wq[i], wk[i], wv[i], WQT, C, rsv);
    k_gemm_qkv<<<dim3(6*N/64, 3*C/64), 256, 0, stream>>>(XB, WQT, QB, KB, VB, C);
    CKERR(30 + 10*i);
    if(i==0){ for(int j = 0; j < 2; j++)
      k_attn_mfma<512><<<dim3(N/64,4),256,0,stream>>>(QB,KB,VB,CT,N,j); }
    if(i==1){ for(int j = 0; j < 2; j++)
      k_attn_mfma<256><<<dim3(N/64,4),256,0,stream>>>(QB,KB,VB,CT,N,j); }
    if(i==2) k_attn128<<<dim3(N/64,4),256,0,stream>>>(QB,KB,VB,CT,N);
    k_ln64<<<4*N, 64, 0, stream>>>(CT, lng[i], lnb[i], C);
    CKERR(32 + 10*i);
    k_cm<<<N, C, 0, stream>>>(CT, CM, C, N);
    k_add<<<6*C, 256, 0, stream>>>(Cc, CM, C, N);
    k_bnstat<<<C, 256, 0, stream>>>(Cc, bng[i], bnb[i], SS, C, N);
    k_bnrelu<<<6*C, 256, 0, stream>>>(Cc, SS, C, N);
    int Co = C/2, S = SPL[i];
    k_b16<<<(6*C*N/8+255)/256, 256, 0, stream>>>(Cc, IB, 6*C*N);
    k_wtr<<<(9*Co*C+255)/256, 256, 0, stream>>>(w_cb[i], WT, Co, C);
    if(S > 1) k_fill<<<(6*Co*N+255)/256, 256, 0, stream>>>(OB, 6*Co*N, 0.f);
    k_conv3_mfma2<<<dim3(N/64, Co/64, 6*S), 256, 0, stream>>>(WT, IB, OB, C, Co, H, H, S);
    CKERR(34 + 10*i);
    Cprev = Co;
  }
  k_up_out<<<6*64, 256, 0, stream>>>(OB, out_f, 64, 64);
  CKERR(90);
  #undef CKERR
}

// Round 10
// 809.914 us; speedup vs baseline: 13.9954x; 1.4086x over previous
//
#include <hip/hip_runtime.h>
#include <hip/hip_bf16.h>

typedef const float* fp;
typedef unsigned short u16;
typedef __attribute__((ext_vector_type(8))) short short8v;   // 8 bf16 (4 VGPR)
typedef __attribute__((ext_vector_type(4))) float f32x4;

__device__ __forceinline__ u16 f2b(float f){       // f32 -> bf16 RNE
  union{float f; unsigned u;} x; x.f = f;
  unsigned r = x.u + 0x7FFFu + ((x.u>>16)&1u);
  return (u16)(r>>16);
}

// ---------- sentinel fill ----------
__global__ __launch_bounds__(256) void k_fill(float* out, int n, float v){
  int i = blockIdx.x*256 + threadIdx.x;
  if(i < n) out[i] = v;
}
// ---------- per-channel bias fill ----------
__global__ __launch_bounds__(256) void k_fillb(float* out, fp bias, int Cout, int N){
  int i = blockIdx.x*256 + threadIdx.x;
  if(i < 6*Cout*N) out[i] = bias[(i/N)%Cout];
}
// ---------- f32 -> bf16 elementwise ----------
__global__ __launch_bounds__(256) void k_b16(fp in, u16* o, int n){
  int i = (blockIdx.x*256 + threadIdx.x)*8;
  if(i >= n) return;
  u16 tmp[8];
  #pragma unroll
  for(int e=0;e<8;e++) tmp[e] = f2b(in[i+e]);
  *(short8v*)(o+i) = *(const short8v*)tmp;
}
// ---------- conv weight transform: w[Cout][Cin][9] f32 -> wt[9][Cout][Cin] bf16 ----------
__global__ __launch_bounds__(256) void k_wtr(fp w, u16* wt, int Cout, int Cin){
  int idx = blockIdx.x*256 + threadIdx.x;
  int cc = Cout*Cin;
  if(idx >= 9*cc) return;
  int tap = idx / cc, rem = idx - tap*cc;
  wt[idx] = f2b(w[(size_t)rem*9 + tap]);
}
// ---------- qkv weight transform -> BT[3C][C] bf16 (Q rows scaled) ----------
__global__ __launch_bounds__(256) void k_wqkvt(fp wq, fp wk, fp wv, u16* bt, int C, float rs){
  int idx = blockIdx.x*256 + threadIdx.x;
  if(idx >= 3*C*C) return;
  int r = idx / C, ci = idx - r*C;
  int sel = r / C, co = r - sel*C;
  float v = (sel==0 ? wq : sel==1 ? wk : wv)[(size_t)ci*C + co];
  bt[idx] = f2b(sel==0 ? v*rs : v);
}

// ---------- input transpose: x [6,64,768] f32 -> h0 [6,768,64] f32 ----------
__global__ __launch_bounds__(256) void k_in_tr(fp x, float* h0){
  int n = blockIdx.x, b = blockIdx.y;
  for(int d = threadIdx.x; d < 768; d += blockDim.x)
    h0[((size_t)b*768 + d)*64 + n] = x[((size_t)b*64 + n)*768 + d];
}

// ---------- tap-decomposed implicit-GEMM MFMA 3x3 conv, split-K ----------
__global__ __launch_bounds__(256) void k_conv3_mfma2(const u16* __restrict__ wt,
    const u16* __restrict__ inb16, float* __restrict__ out,
    int Cin, int Cout, int H, int W, int S){
  const int N = H*W;
  __shared__ u16 As[64*40];
  __shared__ u16 Bs[64*40];
  int t = threadIdx.x, wid = t>>6, lane = t&63, l15 = lane&15, g = lane>>4;
  int b = blockIdx.z / S, s = blockIdx.z % S;
  int co0 = blockIdx.y*64, px0 = blockIdx.x*64;
  int ciN = Cin/S, ci0 = s*ciN;
  const u16* inb = inb16 + (size_t)b*Cin*N;
  int arow = t>>2, acol = (t&3)*8;
  int bpx = t&63, boct = t>>6;
  int p = px0 + bpx, py = p/W, px_ = p - py*W;
  int nc = ciN >> 5, nk = 9*nc;
  f32x4 acc[4];
  #pragma unroll
  for(int i=0;i<4;i++) acc[i] = f32x4{0.f,0.f,0.f,0.f};
  short8v av; u16 bt[8];

  #define PREF(ks) { int tap = (ks)/nc; int c0 = ((ks) - tap*nc)<<5;                     \
      int dy = tap/3 - 1, dx = tap - (tap/3)*3 - 1;                                      \
      av = *(const short8v*)(wt + ((size_t)tap*Cout + co0 + arow)*Cin + ci0 + c0 + acol);\
      bool val = ((unsigned)(py+dy) < (unsigned)H) && ((unsigned)(px_+dx) < (unsigned)W);\
      const u16* bp = inb + (size_t)(ci0 + c0 + boct*8)*N + (p + dy*W + dx);             \
      _Pragma("unroll") for(int e=0;e<8;e++) bt[e] = val ? bp[(size_t)e*N] : (u16)0; }

  PREF(0);
  for(int ks = 0; ks < nk; ks++){
    __syncthreads();
    *(short8v*)(As + arow*40 + acol) = av;
    *(short8v*)(Bs + bpx*40 + boct*8) = *(const short8v*)bt;
    __syncthreads();
    if(ks+1 < nk) PREF(ks+1);
    short8v a = *(const short8v*)(As + (wid*16+l15)*40 + 8*g);
    #pragma unroll
    for(int pt=0; pt<4; pt++){
      short8v bf = *(const short8v*)(Bs + (pt*16+l15)*40 + 8*g);
      acc[pt] = __builtin_amdgcn_mfma_f32_16x16x32_bf16(a, bf, acc[pt], 0,0,0);
    }
  }
  #undef PREF
  #pragma unroll
  for(int pt=0; pt<4; pt++){
    #pragma unroll
    for(int r=0; r<4; r++){
      size_t o = ((size_t)b*Cout + co0 + wid*16 + 4*g + r)*N + px0 + pt*16 + l15;
      if(S == 1) out[o] = acc[pt][r];
      else atomicAdd(out + o, acc[pt][r]);
    }
  }
}

// ---------- QKV projection GEMM: XB[6N][C] @ BT[3C][C]^T -> Q,K bf16; V stored TRANSPOSED ----------
__global__ __launch_bounds__(256) void k_gemm_qkv(const u16* __restrict__ XB,
    const u16* __restrict__ BT, u16* __restrict__ Qo, u16* __restrict__ Ko,
    u16* __restrict__ Vo, int C, int Nn){
  __shared__ u16 As[64*40], Bs[64*40];
  int t = threadIdx.x, wid = t>>6, lane = t&63, l15 = lane&15, g = lane>>4;
  int r0 = blockIdx.x*64, c0 = blockIdx.y*64;
  int arow = t>>2, acol = (t&3)*8;
  int nk = C/32;
  f32x4 acc[4];
  #pragma unroll
  for(int i=0;i<4;i++) acc[i] = f32x4{0.f,0.f,0.f,0.f};
  short8v av = *(const short8v*)(XB + (size_t)(r0+arow)*C + acol);
  short8v bv = *(const short8v*)(BT + (size_t)(c0+arow)*C + acol);
  for(int ks = 0; ks < nk; ks++){
    __syncthreads();
    *(short8v*)(As + arow*40 + acol) = av;
    *(short8v*)(Bs + arow*40 + acol) = bv;
    __syncthreads();
    if(ks+1 < nk){
      int k0 = (ks+1)*32;
      av = *(const short8v*)(XB + (size_t)(r0+arow)*C + k0 + acol);
      bv = *(const short8v*)(BT + (size_t)(c0+arow)*C + k0 + acol);
    }
    short8v a = *(const short8v*)(As + (wid*16+l15)*40 + 8*g);
    #pragma unroll
    for(int pt=0; pt<4; pt++){
      short8v bf = *(const short8v*)(Bs + (pt*16+l15)*40 + 8*g);
      acc[pt] = __builtin_amdgcn_mfma_f32_16x16x32_bf16(a, bf, acc[pt], 0,0,0);
    }
  }
  int sel = c0 / C, cb = c0 - sel*C;
  if(sel < 2){
    u16* ob = sel==0 ? Qo : Ko;
    #pragma unroll
    for(int pt=0; pt<4; pt++){
      #pragma unroll
      for(int r=0; r<4; r++)
        ob[(size_t)(r0 + wid*16 + 4*g + r)*C + cb + pt*16 + l15] = f2b(acc[pt][r]);
    }
  }else{
    int b = r0 / Nn, nb = r0 - b*Nn;     // r0 % 64 == 0, Nn % 64 == 0 -> b fixed in block
    #pragma unroll
    for(int pt=0; pt<4; pt++){
      #pragma unroll
      for(int r=0; r<4; r++)
        Vo[((size_t)b*C + cb + pt*16 + l15)*Nn + nb + wid*16 + 4*g + r] = f2b(acc[pt][r]);
    }
  }
}

// ---------- 1x1 conv at LOW res ----------
__global__ void k_conv1_low(const float* __restrict__ in, fp w, fp bias,
                            float* __restrict__ out, int Cin, int Cout, int N1){
  int bc = blockIdx.x; int b = bc / Cout; int co = bc % Cout;
  extern __shared__ float ws[];
  for(int i = threadIdx.x; i < Cin; i += blockDim.x) ws[i] = w[(size_t)co*Cin + i];
  __syncthreads();
  const float* inb = in + (size_t)b*Cin*N1;
  float bv = bias[co];
  for(int p = threadIdx.x; p < N1; p += blockDim.x){
    float acc = bv;
    for(int ci = 0; ci < Cin; ci++) acc += inb[(size_t)ci*N1 + p] * ws[ci];
    out[((size_t)b*Cout + co)*N1 + p] = acc;
  }
}

// ---------- concat channels with up2 replication of low-res part ----------
__global__ __launch_bounds__(256) void k_concat_up(const float* __restrict__ a, fp skip,
                                                   float* __restrict__ cat,
                                                   int Ca, int Cs, int N2, int W2){
  int bc = blockIdx.x; int C = Ca + Cs; int b = bc / C; int c = bc % C;
  float* o = cat + (size_t)bc*N2;
  if(c < Ca){
    const float* s = a + ((size_t)b*Ca + c)*(N2/4);
    int W1 = W2/2;
    for(int n = threadIdx.x; n < N2; n += blockDim.x){
      int y = n / W2, x = n % W2;
      o[n] = s[(y>>1)*W1 + (x>>1)];
    }
  }else{
    fp s = skip + ((size_t)b*Cs + (c-Ca))*N2;
    for(int n = threadIdx.x; n < N2; n += blockDim.x) o[n] = s[n];
  }
}

// ---------- tiled transpose+bf16: [6][C][N] f32 -> [6][N][C] bf16 ----------
__global__ __launch_bounds__(256) void k_trb(const float* __restrict__ src, u16* __restrict__ dst,
                                             int C, int N){
  __shared__ float tb[32][33];
  int b = blockIdx.z;
  int c0 = blockIdx.y*32, n0 = blockIdx.x*32;
  int tx = threadIdx.x & 31, ty = threadIdx.x >> 5;
  for(int i = ty; i < 32; i += 8) tb[i][tx] = src[((size_t)b*C + c0+i)*N + n0+tx];
  __syncthreads();
  for(int i = ty; i < 32; i += 8) dst[((size_t)b*N + n0+i)*C + c0+tx] = f2b(tb[tx][i]);
}

// ---------- MFMA flash attn C=128: KVB=64, j in grid.z, VT input, prefetch, defer-max ----------
__global__ __launch_bounds__(256) void k_attn128(const u16* __restrict__ Q,
                                                 const u16* __restrict__ K,
                                                 const u16* __restrict__ VT,
                                                 float* __restrict__ ctxn, int N){
  constexpr int C = 128, KVB = 64, KP = C+8, VP = KVB+8;
  __shared__ u16 Ks[KVB*KP];      // [m][c]
  __shared__ u16 Vt[C*VP];        // [c][m]
  __shared__ u16 ps[4][16*VP];
  int t = threadIdx.x, wid = t>>6, lane = t&63, l15 = lane&15, g = lane>>4;
  int p = blockIdx.y, q0 = (blockIdx.x*4 + wid)*16, j = blockIdx.z;
  const u16* Qb = Q + ((size_t)(p+1)*N + q0)*C;
  const u16* Kb = K  + (size_t)(p + (j?2:0))*N*C;   // [N][C]
  const u16* Vb = VT + (size_t)(p + (j?2:0))*C*N;   // [C][N]
  short8v qf[4];
  #pragma unroll
  for(int kk = 0; kk < 4; kk++)
    qf[kk] = *(const short8v*)(Qb + (size_t)l15*C + kk*32 + 8*g);
  f32x4 acc[8];
  #pragma unroll
  for(int i=0;i<8;i++) acc[i] = f32x4{0.f,0.f,0.f,0.f};
  float m[4] = {-1e30f,-1e30f,-1e30f,-1e30f};
  float l[4] = {0.f,0.f,0.f,0.f};
  short8v kpre[4], vpre[4];

  #define APREF(M0) { _Pragma("unroll") for(int i=0;i<4;i++){                  \
        int idx = t*8 + i*2048; int mm = idx>>7, cc = idx&127;                 \
        kpre[i] = *(const short8v*)(Kb + (size_t)((M0)+mm)*C + cc); }          \
      _Pragma("unroll") for(int i=0;i<4;i++){                                  \
        int idx = t*8 + i*2048; int c = idx>>6, mo = idx&63;                   \
        vpre[i] = *(const short8v*)(Vb + (size_t)c*N + (M0) + mo); } }

  APREF(0);
  for(int m0 = 0; m0 < N; m0 += KVB){
    __syncthreads();
    #pragma unroll
    for(int i=0;i<4;i++){ int idx = t*8 + i*2048; int mm = idx>>7, cc = idx&127;
      *(short8v*)(Ks + mm*KP + cc) = kpre[i]; }
    #pragma unroll
    for(int i=0;i<4;i++){ int idx = t*8 + i*2048; int c = idx>>6, mo = idx&63;
      *(short8v*)(Vt + c*VP + mo) = vpre[i]; }
    __syncthreads();
    if(m0 + KVB < N) APREF(m0 + KVB);
    f32x4 s[4];
    #pragma unroll
    for(int h=0; h<4; h++){
      s[h] = f32x4{0.f,0.f,0.f,0.f};
      #pragma unroll
      for(int kk=0; kk<4; kk++){
        short8v kf = *(const short8v*)(Ks + (h*16+l15)*KP + kk*32 + 8*g);
        s[h] = __builtin_amdgcn_mfma_f32_16x16x32_bf16(qf[kk], kf, s[h], 0,0,0);
      }
    }
    float pmax[4]; bool need = false;
    #pragma unroll
    for(int r=0; r<4; r++){
      float mx = fmaxf(fmaxf(s[0][r],s[1][r]), fmaxf(s[2][r],s[3][r]));
      #pragma unroll
      for(int off=1; off<16; off<<=1) mx = fmaxf(mx, __shfl_xor(mx, off));
      pmax[r] = mx; need |= (mx > m[r] + 8.f);
    }
    if(__any((int)need)){
      #pragma unroll
      for(int r=0; r<4; r++){
        float mnew = fmaxf(m[r], pmax[r]);
        float scl = __expf(m[r] - mnew);
        l[r] *= scl; m[r] = mnew;
        #pragma unroll
        for(int ct=0; ct<8; ct++) acc[ct][r] *= scl;
      }
    }
    #pragma unroll
    for(int r=0; r<4; r++){
      float psum = 0.f;
      #pragma unroll
      for(int h=0; h<4; h++){
        float e = __expf(s[h][r] - m[r]); psum += e;
        ps[wid][(4*g+r)*VP + h*16 + l15] = f2b(e);
      }
      #pragma unroll
      for(int off=1; off<16; off<<=1) psum += __shfl_xor(psum, off);
      l[r] += psum;
    }
    #pragma unroll
    for(int ks=0; ks<2; ks++){
      short8v pa = *(const short8v*)(ps[wid] + l15*VP + ks*32 + 8*g);
      #pragma unroll
      for(int ct=0; ct<8; ct++){
        short8v vb = *(const short8v*)(Vt + (ct*16+l15)*VP + ks*32 + 8*g);
        acc[ct] = __builtin_amdgcn_mfma_f32_16x16x32_bf16(pa, vb, acc[ct], 0,0,0);
      }
    }
  }
  #undef APREF
  float inv[4];
  #pragma unroll
  for(int r=0; r<4; r++) inv[r] = 0.5f/l[r];
  #pragma unroll
  for(int ct=0; ct<8; ct++){
    int c = ct*16 + l15;
    #pragma unroll
    for(int r=0; r<4; r++)
      atomicAdd(&ctxn[((size_t)p*N + q0 + 4*g + r)*C + c], acc[ct][r]*inv[r]);
  }
}

// ---------- MFMA flash attn (C=256/512), j in grid.z, VT input ----------
template<int C>
__global__ __launch_bounds__(256) void k_attn_mfma(const u16* __restrict__ Q,
                                                   const u16* __restrict__ K,
                                                   const u16* __restrict__ VT,
                                                   float* __restrict__ ctxn, int N){
  constexpr int KP = C + 8;
  __shared__ u16 Ks[32*KP];
  __shared__ u16 Vt[C*40];
  __shared__ u16 ps[4][16*40];
  int t = threadIdx.x, wid = t>>6, lane = t&63;
  int l15 = lane&15, g = lane>>4;
  int p = blockIdx.y, j = blockIdx.z;
  int q0 = (blockIdx.x*4 + wid)*16;
  const u16* Qb = Q + ((size_t)(p+1)*N + q0)*C;
  const u16* Kb = K  + (size_t)(p + (j?2:0))*N*C;
  const u16* Vb = VT + (size_t)(p + (j?2:0))*C*N;

  short8v qf[C/32];
  #pragma unroll
  for(int kk = 0; kk < C/32; kk++)
    qf[kk] = *(const short8v*)(Qb + (size_t)l15*C + kk*32 + 8*g);

  f32x4 acc[C/16];
  #pragma unroll
  for(int i = 0; i < C/16; i++) acc[i] = f32x4{0.f,0.f,0.f,0.f};
  float mrow[4] = {-1e30f,-1e30f,-1e30f,-1e30f};
  float lrow[4] = {0.f,0.f,0.f,0.f};

  for(int m0 = 0; m0 < N; m0 += 32){
    __syncthreads();
    for(int idx = t*8; idx < 32*C; idx += 2048){
      int m = idx/C, c = idx - m*C;
      *(short8v*)(Ks + m*KP + c) = *(const short8v*)(Kb + (size_t)(m0+m)*C + c);
    }
    for(int idx = t*8; idx < 32*C; idx += 2048){
      int c = idx >> 5, mo = idx & 31;
      *(short8v*)(Vt + c*40 + mo) = *(const short8v*)(Vb + (size_t)c*N + m0 + mo);
    }
    __syncthreads();
    f32x4 s0 = {0.f,0.f,0.f,0.f}, s1 = {0.f,0.f,0.f,0.f};
    #pragma unroll
    for(int kk = 0; kk < C/32; kk++){
      short8v k0 = *(const short8v*)(Ks + l15*KP      + kk*32 + 8*g);
      short8v k1 = *(const short8v*)(Ks + (16+l15)*KP + kk*32 + 8*g);
      s0 = __builtin_amdgcn_mfma_f32_16x16x32_bf16(qf[kk], k0, s0, 0,0,0);
      s1 = __builtin_amdgcn_mfma_f32_16x16x32_bf16(qf[kk], k1, s1, 0,0,0);
    }
    float scl[4];
    #pragma unroll
    for(int r = 0; r < 4; r++){
      float mx = fmaxf(s0[r], s1[r]);
      #pragma unroll
      for(int off = 1; off < 16; off <<= 1) mx = fmaxf(mx, __shfl_xor(mx, off));
      float mnew = fmaxf(mrow[r], mx);
      scl[r] = __expf(mrow[r] - mnew);
      float e0 = __expf(s0[r] - mnew), e1 = __expf(s1[r] - mnew);
      float psum = e0 + e1;
      #pragma unroll
      for(int off = 1; off < 16; off <<= 1) psum += __shfl_xor(psum, off);
      lrow[r] = lrow[r]*scl[r] + psum;
      mrow[r] = mnew;
      int m = 4*g + r;
      ps[wid][m*40 + l15]      = f2b(e0);
      ps[wid][m*40 + 16 + l15] = f2b(e1);
    }
    #pragma unroll
    for(int ct = 0; ct < C/16; ct++){
      #pragma unroll
      for(int r = 0; r < 4; r++) acc[ct][r] *= scl[r];
    }
    short8v pa = *(const short8v*)(ps[wid] + l15*40 + 8*g);
    #pragma unroll
    for(int ct = 0; ct < C/16; ct++){
      short8v vb = *(const short8v*)(Vt + (ct*16+l15)*40 + 8*g);
      acc[ct] = __builtin_amdgcn_mfma_f32_16x16x32_bf16(pa, vb, acc[ct], 0,0,0);
    }
  }
  #pragma unroll
  for(int ct = 0; ct < C/16; ct++){
    int c = ct*16 + l15;
    #pragma unroll
    for(int r = 0; r < 4; r++){
      int m = 4*g + r;
      atomicAdd(&ctxn[((size_t)p*N + q0 + m)*C + c], 0.5f*acc[ct][r]/lrow[r]);
    }
  }
}

// ---------- LayerNorm over C, wave-only ----------
__global__ __launch_bounds__(64) void k_ln64(float* __restrict__ ctxn, fp lng, fp lnb, int C){
  float* row = ctxn + (size_t)blockIdx.x*C;
  int t = threadIdx.x;
  float s = 0.f, s2 = 0.f;
  for(int c = t; c < C; c += 64){ float v = row[c]; s += v; s2 += v*v; }
  #pragma unroll
  for(int off = 32; off > 0; off >>= 1){ s += __shfl_xor(s, off); s2 += __shfl_xor(s2, off); }
  float m = s/(float)C, var = s2/(float)C - m*m;
  float ri = rsqrtf(var + 1e-5f);
  for(int c = t; c < C; c += 64) row[c] = (row[c] - m)*ri*lng[c] + lnb[c];
}

// ---------- cm[n][c] = mean_p ctxn[p][n][c] ----------
__global__ void k_cm(const float* __restrict__ ctxn, float* __restrict__ cm, int C, int N){
  int n = blockIdx.x;
  for(int c = threadIdx.x; c < C; c += blockDim.x){
    float s = 0.25f*( ctxn[((size_t)0*N + n)*C + c] + ctxn[((size_t)1*N + n)*C + c]
                    + ctxn[((size_t)2*N + n)*C + c] + ctxn[((size_t)3*N + n)*C + c]);
    cm[(size_t)n*C + c] = s;
  }
}

// ---------- h[b][c][n] += cm[n][c] ----------
__global__ __launch_bounds__(256) void k_add(float* __restrict__ h, const float* __restrict__ cm,
                                             int C, int N){
  int bc = blockIdx.x; int c = bc % C;
  float* hp = h + (size_t)bc*N;
  for(int n = threadIdx.x; n < N; n += blockDim.x) hp[n] += cm[(size_t)n*C + c];
}

// ---------- batch-norm stats per channel over (b,n) ----------
__global__ __launch_bounds__(256) void k_bnstat(const float* __restrict__ h, fp bng, fp bnb,
                                                float* __restrict__ ssout, int C, int N){
  __shared__ float red[8], red2[8];
  int c = blockIdx.x; int t = threadIdx.x;
  float s = 0.f, s2 = 0.f;
  for(int b = 0; b < 6; b++){
    const float* hp = h + ((size_t)b*C + c)*N;
    for(int n = t; n < N; n += blockDim.x){ float v = hp[n]; s += v; s2 += v*v; }
  }
  for(int o = 32; o > 0; o >>= 1){ s += __shfl_down(s, o); s2 += __shfl_down(s2, o); }
  int lane = t & 63, wid = t >> 6;
  if(lane == 0){ red[wid] = s; red2[wid] = s2; }
  __syncthreads();
  if(t == 0){
    float S = 0.f, S2 = 0.f; int nw = blockDim.x >> 6;
    for(int i = 0; i < nw; i++){ S += red[i]; S2 += red2[i]; }
    float inv = 1.f/(6.f*(float)N);
    float m = S*inv, var = S2*inv - m*m;
    float sc = bng[c]*rsqrtf(var + 1e-5f);
    ssout[c] = sc; ssout[C + c] = bnb[c] - m*sc;
  }
}

// ---------- BN apply + ReLU, in place ----------
__global__ __launch_bounds__(256) void k_bnrelu(float* __restrict__ h, const float* __restrict__ ssin,
                                                int C, int N){
  int bc = blockIdx.x; int c = bc % C;
  float sc = ssin[c], sh = ssin[C + c];
  float* hp = h + (size_t)bc*N;
  for(int n = threadIdx.x; n < N; n += blockDim.x){
    float v = hp[n]*sc + sh; hp[n] = v > 0.f ? v : 0.f;
  }
}

// ---------- final up2 + f32 store ----------
__global__ __launch_bounds__(256) void k_up_out(const float* __restrict__ in, float* out,
                                                int H, int W){
  int bc = blockIdx.x;
  const float* ip = in + (size_t)bc*H*W;
  float* op = out + (size_t)bc*4*H*W;
  int W2 = 2*W, N2 = 4*H*W;
  for(int p = threadIdx.x; p < N2; p += blockDim.x){
    int y = p / W2, x = p % W2;
    op[p] = ip[(y>>1)*W + (x>>1)];
  }
}

extern "C" void kernel_launch(void* const* d_in, const int* in_sizes, int n_in,
                              void* d_out, int out_size, void* d_ws, size_t ws_size,
                              hipStream_t stream){
  float* out_f = (float*)d_out;
  static const int EXP[36] = {294912,393216,786432,1572864,3538944,512,
    131072,256,262144,262144,262144,512,512,512,512,1179648,
    32768,128,65536,65536,65536,256,256,256,256,294912,
    8192,64,16384,16384,16384,128,128,128,128,73728};
  bool ok = (n_in == 36) && (out_size == 6291456);
  if(ok) for(int i = 0; i < 36; i++) if(in_sizes[i] != EXP[i]){ ok = false; break; }
  if(!ok){
    k_fill<<<(out_size+255)/256, 256, 0, stream>>>(out_f, out_size, 10.0f);
    return;
  }
  const size_t R = 3145728;
  const size_t NEED = (5*R + 1024)*sizeof(float);
  if(ws_size < NEED){
    k_fill<<<(out_size+255)/256, 256, 0, stream>>>(out_f, out_size, 100.0f);
    return;
  }
  (void)hipGetLastError();
  #define CKERR(code) do{ if(hipGetLastError() != hipSuccess){ \
      k_fill<<<(out_size+255)/256, 256, 0, stream>>>(out_f, out_size, (float)(code)); \
      return; } }while(0)

  fp x = (fp)d_in[0];
  fp skip[3]  = {(fp)d_in[1],(fp)d_in[2],(fp)d_in[3]};
  fp w_sc = (fp)d_in[4], b_sc = (fp)d_in[5];
  fp w_up[3] = {(fp)d_in[6], (fp)d_in[16],(fp)d_in[26]};
  fp b_up[3] = {(fp)d_in[7], (fp)d_in[17],(fp)d_in[27]};
  fp wq[3]   = {(fp)d_in[8], (fp)d_in[18],(fp)d_in[28]};
  fp wk[3]   = {(fp)d_in[9], (fp)d_in[19],(fp)d_in[29]};
  fp wv[3]   = {(fp)d_in[10],(fp)d_in[20],(fp)d_in[30]};
  fp lng[3]  = {(fp)d_in[11],(fp)d_in[21],(fp)d_in[31]};
  fp lnb[3]  = {(fp)d_in[12],(fp)d_in[22],(fp)d_in[32]};
  fp bng[3]  = {(fp)d_in[13],(fp)d_in[23],(fp)d_in[33]};
  fp bnb[3]  = {(fp)d_in[14],(fp)d_in[24],(fp)d_in[34]};
  fp w_cb[3] = {(fp)d_in[15],(fp)d_in[25],(fp)d_in[35]};

  float* Wp = (float*)d_ws;
  float *Cc = Wp, *CT = Wp + R;
  u16 *QB = (u16*)(Wp + 2*R), *KB = (u16*)(Wp + 3*R), *VB = (u16*)(Wp + 4*R);
  float *SS = Wp + 5*R;
  float *OB = Wp + R, *Bf = Wp + 2*R, *CM = Wp + 2*R;   // aliases (liveness-verified)
  u16 *XB  = QB + R;        // QB region upper half
  u16 *WQT = KB + R;        // KB region upper half
  u16 *WT = KB, *IB = VB;   // conv weight/input bf16 (K,V dead at conv time)

  // stage 0
  k_in_tr<<<dim3(64,6),256,0,stream>>>(x, Cc);
  k_b16<<<(294912/8+255)/256, 256, 0, stream>>>(Cc, IB, 294912);
  k_wtr<<<(9*512*768+255)/256, 256, 0, stream>>>(w_sc, WT, 512, 768);
  k_fillb<<<(6*512*64+255)/256, 256, 0, stream>>>(OB, b_sc, 512, 64);
  k_conv3_mfma2<<<dim3(1,8,6*8), 256, 0, stream>>>(WT, IB, OB, 768, 512, 8, 8, 8);
  CKERR(20);

  const int Cskip[3] = {256,128,64};
  const int Hs[3]    = {16,32,64};
  const int SPL[3]   = {4,2,1};
  int Cprev = 512;
  for(int i = 0; i < 3; i++){
    int H = Hs[i], N = H*H;
    int N1 = N/4;
    int Cup = Cprev/2;
    int C = Cup + Cskip[i];
    k_conv1_low<<<6*Cup, (N1<256?N1:256), Cprev*4, stream>>>(OB, w_up[i], b_up[i], Bf, Cprev, Cup, N1);
    k_concat_up<<<6*C, 256, 0, stream>>>(Bf, skip[i], Cc, Cup, Cskip[i], N, H);
    k_trb<<<dim3(N/32, C/32, 6), 256, 0, stream>>>(Cc, XB, C, N);
    float rsv = 1.f/sqrtf((float)C);
    k_wqkvt<<<(3*C*C+255)/256, 256, 0, stream>>>(wq[i], wk[i], wv[i], WQT, C, rsv);
    k_gemm_qkv<<<dim3(6*N/64, 3*C/64), 256, 0, stream>>>(XB, WQT, QB, KB, VB, C, N);
    CKERR(30 + 10*i);
    k_fill<<<(4*N*C+255)/256, 256, 0, stream>>>(CT, 4*N*C, 0.f);
    if(i==0) k_attn_mfma<512><<<dim3(N/64,4,2),256,0,stream>>>(QB,KB,VB,CT,N);
    if(i==1) k_attn_mfma<256><<<dim3(N/64,4,2),256,0,stream>>>(QB,KB,VB,CT,N);
    if(i==2) k_attn128<<<dim3(N/64,4,2),256,0,stream>>>(QB,KB,VB,CT,N);
    k_ln64<<<4*N, 64, 0, stream>>>(CT, lng[i], lnb[i], C);
    CKERR(32 + 10*i);
    k_cm<<<N, C, 0, stream>>>(CT, CM, C, N);
    k_add<<<6*C, 256, 0, stream>>>(Cc, CM, C, N);
    k_bnstat<<<C, 256, 0, stream>>>(Cc, bng[i], bnb[i], SS, C, N);
    k_bnrelu<<<6*C, 256, 0, stream>>>(Cc, SS, C, N);
    int Co = C/2, S = SPL[i];
    k_b16<<<(6*C*N/8+255)/256, 256, 0, stream>>>(Cc, IB, 6*C*N);
    k_wtr<<<(9*Co*C+255)/256, 256, 0, stream>>>(w_cb[i], WT, Co, C);
    if(S > 1) k_fill<<<(6*Co*N+255)/256, 256, 0, stream>>>(OB, 6*Co*N, 0.f);
    k_conv3_mfma2<<<dim3(N/64, Co/64, 6*S), 256, 0, stream>>>(WT, IB, OB, C, Co, H, H, S);
    CKERR(34 + 10*i);
    Cprev = Co;
  }
  k_up_out<<<6*64, 256, 0, stream>>>(OB, out_f, 64, 64);
  CKERR(90);
  #undef CKERR
}

// Round 11
// 751.378 us; speedup vs baseline: 15.0857x; 1.0779x over previous
//
#include <hip/hip_runtime.h>
#include <hip/hip_bf16.h>

typedef const float* fp;
typedef unsigned short u16;
typedef __attribute__((ext_vector_type(8))) short short8v;   // 8 bf16 (4 VGPR)
typedef __attribute__((ext_vector_type(4))) float f32x4;

__device__ __forceinline__ u16 f2b(float f){       // f32 -> bf16 RNE
  union{float f; unsigned u;} x; x.f = f;
  unsigned r = x.u + 0x7FFFu + ((x.u>>16)&1u);
  return (u16)(r>>16);
}

// ---------- sentinel fill ----------
__global__ __launch_bounds__(256) void k_fill(float* out, int n, float v){
  int i = blockIdx.x*256 + threadIdx.x;
  if(i < n) out[i] = v;
}
// ---------- per-channel bias fill ----------
__global__ __launch_bounds__(256) void k_fillb(float* out, fp bias, int Cout, int N){
  int i = blockIdx.x*256 + threadIdx.x;
  if(i < 6*Cout*N) out[i] = bias[(i/N)%Cout];
}
// ---------- f32 -> bf16 elementwise ----------
__global__ __launch_bounds__(256) void k_b16(fp in, u16* o, int n){
  int i = (blockIdx.x*256 + threadIdx.x)*8;
  if(i >= n) return;
  u16 tmp[8];
  #pragma unroll
  for(int e=0;e<8;e++) tmp[e] = f2b(in[i+e]);
  *(short8v*)(o+i) = *(const short8v*)tmp;
}
// ---------- conv weight transform: w[Cout][Cin][9] f32 -> wt[9][Cout][Cin] bf16 ----------
__global__ __launch_bounds__(256) void k_wtr(fp w, u16* wt, int Cout, int Cin){
  int idx = blockIdx.x*256 + threadIdx.x;
  int cc = Cout*Cin;
  if(idx >= 9*cc) return;
  int tap = idx / cc, rem = idx - tap*cc;
  wt[idx] = f2b(w[(size_t)rem*9 + tap]);
}
// ---------- qkv weight transform -> BT[3C][C] bf16 (Q rows scaled) ----------
__global__ __launch_bounds__(256) void k_wqkvt(fp wq, fp wk, fp wv, u16* bt, int C, float rs){
  int idx = blockIdx.x*256 + threadIdx.x;
  if(idx >= 3*C*C) return;
  int r = idx / C, ci = idx - r*C;
  int sel = r / C, co = r - sel*C;
  float v = (sel==0 ? wq : sel==1 ? wk : wv)[(size_t)ci*C + co];
  bt[idx] = f2b(sel==0 ? v*rs : v);
}

// ---------- input transpose: x [6,64,768] f32 -> h0 [6,768,64] f32 ----------
__global__ __launch_bounds__(256) void k_in_tr(fp x, float* h0){
  int n = blockIdx.x, b = blockIdx.y;
  for(int d = threadIdx.x; d < 768; d += blockDim.x)
    h0[((size_t)b*768 + d)*64 + n] = x[((size_t)b*64 + n)*768 + d];
}

// ---------- tap-decomposed implicit-GEMM MFMA 3x3 conv, split-K ----------
__global__ __launch_bounds__(256) void k_conv3_mfma2(const u16* __restrict__ wt,
    const u16* __restrict__ inb16, float* __restrict__ out,
    int Cin, int Cout, int H, int W, int S){
  const int N = H*W;
  __shared__ u16 As[64*40];
  __shared__ u16 Bs[64*40];
  int t = threadIdx.x, wid = t>>6, lane = t&63, l15 = lane&15, g = lane>>4;
  int b = blockIdx.z / S, s = blockIdx.z % S;
  int co0 = blockIdx.y*64, px0 = blockIdx.x*64;
  int ciN = Cin/S, ci0 = s*ciN;
  const u16* inb = inb16 + (size_t)b*Cin*N;
  int arow = t>>2, acol = (t&3)*8;
  int bpx = t&63, boct = t>>6;
  int p = px0 + bpx, py = p/W, px_ = p - py*W;
  int nc = ciN >> 5, nk = 9*nc;
  f32x4 acc[4];
  #pragma unroll
  for(int i=0;i<4;i++) acc[i] = f32x4{0.f,0.f,0.f,0.f};
  short8v av; u16 bt[8];

  #define PREF(ks) { int tap = (ks)/nc; int c0 = ((ks) - tap*nc)<<5;                     \
      int dy = tap/3 - 1, dx = tap - (tap/3)*3 - 1;                                      \
      av = *(const short8v*)(wt + ((size_t)tap*Cout + co0 + arow)*Cin + ci0 + c0 + acol);\
      bool val = ((unsigned)(py+dy) < (unsigned)H) && ((unsigned)(px_+dx) < (unsigned)W);\
      const u16* bp = inb + (size_t)(ci0 + c0 + boct*8)*N + (p + dy*W + dx);             \
      _Pragma("unroll") for(int e=0;e<8;e++) bt[e] = val ? bp[(size_t)e*N] : (u16)0; }

  PREF(0);
  for(int ks = 0; ks < nk; ks++){
    __syncthreads();
    *(short8v*)(As + arow*40 + acol) = av;
    *(short8v*)(Bs + bpx*40 + boct*8) = *(const short8v*)bt;
    __syncthreads();
    if(ks+1 < nk) PREF(ks+1);
    short8v a = *(const short8v*)(As + (wid*16+l15)*40 + 8*g);
    #pragma unroll
    for(int pt=0; pt<4; pt++){
      short8v bf = *(const short8v*)(Bs + (pt*16+l15)*40 + 8*g);
      acc[pt] = __builtin_amdgcn_mfma_f32_16x16x32_bf16(a, bf, acc[pt], 0,0,0);
    }
  }
  #undef PREF
  #pragma unroll
  for(int pt=0; pt<4; pt++){
    #pragma unroll
    for(int r=0; r<4; r++){
      size_t o = ((size_t)b*Cout + co0 + wid*16 + 4*g + r)*N + px0 + pt*16 + l15;
      if(S == 1) out[o] = acc[pt][r];
      else atomicAdd(out + o, acc[pt][r]);
    }
  }
}

// ---------- QKV projection GEMM: XB[6N][C] @ BT[3C][C]^T -> Q,K bf16; V stored TRANSPOSED ----------
__global__ __launch_bounds__(256) void k_gemm_qkv(const u16* __restrict__ XB,
    const u16* __restrict__ BT, u16* __restrict__ Qo, u16* __restrict__ Ko,
    u16* __restrict__ Vo, int C, int Nn){
  __shared__ u16 As[64*40], Bs[64*40];
  int t = threadIdx.x, wid = t>>6, lane = t&63, l15 = lane&15, g = lane>>4;
  int r0 = blockIdx.x*64, c0 = blockIdx.y*64;
  int arow = t>>2, acol = (t&3)*8;
  int nk = C/32;
  f32x4 acc[4];
  #pragma unroll
  for(int i=0;i<4;i++) acc[i] = f32x4{0.f,0.f,0.f,0.f};
  short8v av = *(const short8v*)(XB + (size_t)(r0+arow)*C + acol);
  short8v bv = *(const short8v*)(BT + (size_t)(c0+arow)*C + acol);
  for(int ks = 0; ks < nk; ks++){
    __syncthreads();
    *(short8v*)(As + arow*40 + acol) = av;
    *(short8v*)(Bs + arow*40 + acol) = bv;
    __syncthreads();
    if(ks+1 < nk){
      int k0 = (ks+1)*32;
      av = *(const short8v*)(XB + (size_t)(r0+arow)*C + k0 + acol);
      bv = *(const short8v*)(BT + (size_t)(c0+arow)*C + k0 + acol);
    }
    short8v a = *(const short8v*)(As + (wid*16+l15)*40 + 8*g);
    #pragma unroll
    for(int pt=0; pt<4; pt++){
      short8v bf = *(const short8v*)(Bs + (pt*16+l15)*40 + 8*g);
      acc[pt] = __builtin_amdgcn_mfma_f32_16x16x32_bf16(a, bf, acc[pt], 0,0,0);
    }
  }
  int sel = c0 / C, cb = c0 - sel*C;
  if(sel < 2){
    u16* ob = sel==0 ? Qo : Ko;
    #pragma unroll
    for(int pt=0; pt<4; pt++){
      #pragma unroll
      for(int r=0; r<4; r++)
        ob[(size_t)(r0 + wid*16 + 4*g + r)*C + cb + pt*16 + l15] = f2b(acc[pt][r]);
    }
  }else{
    int b = r0 / Nn, nb = r0 - b*Nn;
    #pragma unroll
    for(int pt=0; pt<4; pt++){
      #pragma unroll
      for(int r=0; r<4; r++)
        Vo[((size_t)b*C + cb + pt*16 + l15)*Nn + nb + wid*16 + 4*g + r] = f2b(acc[pt][r]);
    }
  }
}

// ---------- 1x1 conv at LOW res ----------
__global__ void k_conv1_low(const float* __restrict__ in, fp w, fp bias,
                            float* __restrict__ out, int Cin, int Cout, int N1){
  int bc = blockIdx.x; int b = bc / Cout; int co = bc % Cout;
  extern __shared__ float ws[];
  for(int i = threadIdx.x; i < Cin; i += blockDim.x) ws[i] = w[(size_t)co*Cin + i];
  __syncthreads();
  const float* inb = in + (size_t)b*Cin*N1;
  float bv = bias[co];
  for(int p = threadIdx.x; p < N1; p += blockDim.x){
    float acc = bv;
    for(int ci = 0; ci < Cin; ci++) acc += inb[(size_t)ci*N1 + p] * ws[ci];
    out[((size_t)b*Cout + co)*N1 + p] = acc;
  }
}

// ---------- concat channels with up2 replication of low-res part ----------
__global__ __launch_bounds__(256) void k_concat_up(const float* __restrict__ a, fp skip,
                                                   float* __restrict__ cat,
                                                   int Ca, int Cs, int N2, int W2){
  int bc = blockIdx.x; int C = Ca + Cs; int b = bc / C; int c = bc % C;
  float* o = cat + (size_t)bc*N2;
  if(c < Ca){
    const float* s = a + ((size_t)b*Ca + c)*(N2/4);
    int W1 = W2/2;
    for(int n = threadIdx.x; n < N2; n += blockDim.x){
      int y = n / W2, x = n % W2;
      o[n] = s[(y>>1)*W1 + (x>>1)];
    }
  }else{
    fp s = skip + ((size_t)b*Cs + (c-Ca))*N2;
    for(int n = threadIdx.x; n < N2; n += blockDim.x) o[n] = s[n];
  }
}

// ---------- tiled transpose+bf16: [6][C][N] f32 -> [6][N][C] bf16 ----------
__global__ __launch_bounds__(256) void k_trb(const float* __restrict__ src, u16* __restrict__ dst,
                                             int C, int N){
  __shared__ float tb[32][33];
  int b = blockIdx.z;
  int c0 = blockIdx.y*32, n0 = blockIdx.x*32;
  int tx = threadIdx.x & 31, ty = threadIdx.x >> 5;
  for(int i = ty; i < 32; i += 8) tb[i][tx] = src[((size_t)b*C + c0+i)*N + n0+tx];
  __syncthreads();
  for(int i = ty; i < 32; i += 8) dst[((size_t)b*N + n0+i)*C + c0+tx] = f2b(tb[tx][i]);
}

// ---------- MFMA flash attn C=128: lane-local l, fast-path max, setprio ----------
__global__ __launch_bounds__(256) void k_attn128(const u16* __restrict__ Q,
                                                 const u16* __restrict__ K,
                                                 const u16* __restrict__ VT,
                                                 float* __restrict__ ctxn, int N){
  constexpr int C = 128, KVB = 64, KP = C+8, VP = KVB+8, PSP = 68;
  __shared__ u16 Ks[KVB*KP];      // [m][c]
  __shared__ u16 Vt[C*VP];        // [c][m]
  __shared__ u16 ps[4][16*PSP];   // stride 68 ush = 34 dw ≡ 2 mod 32: conflict-free
  int t = threadIdx.x, wid = t>>6, lane = t&63, l15 = lane&15, g = lane>>4;
  int p = blockIdx.y, q0 = (blockIdx.x*4 + wid)*16, j = blockIdx.z;
  const u16* Qb = Q + ((size_t)(p+1)*N + q0)*C;
  const u16* Kb = K  + (size_t)(p + (j?2:0))*N*C;   // [N][C]
  const u16* Vb = VT + (size_t)(p + (j?2:0))*C*N;   // [C][N]
  short8v qf[4];
  #pragma unroll
  for(int kk = 0; kk < 4; kk++)
    qf[kk] = *(const short8v*)(Qb + (size_t)l15*C + kk*32 + 8*g);
  f32x4 acc[8];
  #pragma unroll
  for(int i=0;i<8;i++) acc[i] = f32x4{0.f,0.f,0.f,0.f};
  float m[4] = {-1e30f,-1e30f,-1e30f,-1e30f};
  float l[4] = {0.f,0.f,0.f,0.f};         // lane-local partial sums (16-lane split)
  short8v kpre[4], vpre[4];

  #define APREF(M0) { _Pragma("unroll") for(int i=0;i<4;i++){                  \
        int idx = t*8 + i*2048; int mm = idx>>7, cc = idx&127;                 \
        kpre[i] = *(const short8v*)(Kb + (size_t)((M0)+mm)*C + cc); }          \
      _Pragma("unroll") for(int i=0;i<4;i++){                                  \
        int idx = t*8 + i*2048; int c = idx>>6, mo = idx&63;                   \
        vpre[i] = *(const short8v*)(Vb + (size_t)c*N + (M0) + mo); } }

  APREF(0);
  for(int m0 = 0; m0 < N; m0 += KVB){
    __syncthreads();
    #pragma unroll
    for(int i=0;i<4;i++){ int idx = t*8 + i*2048; int mm = idx>>7, cc = idx&127;
      *(short8v*)(Ks + mm*KP + cc) = kpre[i]; }
    #pragma unroll
    for(int i=0;i<4;i++){ int idx = t*8 + i*2048; int c = idx>>6, mo = idx&63;
      *(short8v*)(Vt + c*VP + mo) = vpre[i]; }
    __syncthreads();
    if(m0 + KVB < N) APREF(m0 + KVB);
    f32x4 s[4];
    __builtin_amdgcn_s_setprio(1);
    #pragma unroll
    for(int h=0; h<4; h++){
      s[h] = f32x4{0.f,0.f,0.f,0.f};
      #pragma unroll
      for(int kk=0; kk<4; kk++){
        short8v kf = *(const short8v*)(Ks + (h*16+l15)*KP + kk*32 + 8*g);
        s[h] = __builtin_amdgcn_mfma_f32_16x16x32_bf16(qf[kk], kf, s[h], 0,0,0);
      }
    }
    __builtin_amdgcn_s_setprio(0);
    // fast-path max: lane-local max + ballot; reduce+rescale only when needed
    float lmax[4]; bool need = false;
    #pragma unroll
    for(int r=0; r<4; r++){
      float a = fmaxf(fmaxf(s[0][r],s[1][r]), fmaxf(s[2][r],s[3][r]));
      lmax[r] = a; need |= (a > m[r] + 8.f);
    }
    if(__any((int)need)){
      #pragma unroll
      for(int r=0; r<4; r++){
        float mx = lmax[r];
        #pragma unroll
        for(int off=1; off<16; off<<=1) mx = fmaxf(mx, __shfl_xor(mx, off));
        float mnew = fmaxf(m[r], mx);
        float scl = __expf(m[r] - mnew);
        l[r] *= scl; m[r] = mnew;
        #pragma unroll
        for(int ct=0; ct<8; ct++) acc[ct][r] *= scl;
      }
    }
    #pragma unroll
    for(int r=0; r<4; r++){
      float ls = 0.f;
      #pragma unroll
      for(int h=0; h<4; h++){
        float e = __expf(s[h][r] - m[r]); ls += e;
        ps[wid][(4*g+r)*PSP + h*16 + l15] = f2b(e);
      }
      l[r] += ls;                         // lane-local; reduced once at end
    }
    __builtin_amdgcn_s_setprio(1);
    #pragma unroll
    for(int ks=0; ks<2; ks++){
      short8v pa = *(const short8v*)(ps[wid] + l15*PSP + ks*32 + 8*g);
      #pragma unroll
      for(int ct=0; ct<8; ct++){
        short8v vb = *(const short8v*)(Vt + (ct*16+l15)*VP + ks*32 + 8*g);
        acc[ct] = __builtin_amdgcn_mfma_f32_16x16x32_bf16(pa, vb, acc[ct], 0,0,0);
      }
    }
    __builtin_amdgcn_s_setprio(0);
  }
  #undef APREF
  float inv[4];
  #pragma unroll
  for(int r=0; r<4; r++){
    float lr = l[r];
    #pragma unroll
    for(int off=1; off<16; off<<=1) lr += __shfl_xor(lr, off);
    inv[r] = 0.5f/lr;
  }
  #pragma unroll
  for(int ct=0; ct<8; ct++){
    int c = ct*16 + l15;
    #pragma unroll
    for(int r=0; r<4; r++)
      atomicAdd(&ctxn[((size_t)p*N + q0 + 4*g + r)*C + c], acc[ct][r]*inv[r]);
  }
}

// ---------- MFMA flash attn (C=256/512), j in grid.z, VT input ----------
template<int C>
__global__ __launch_bounds__(256) void k_attn_mfma(const u16* __restrict__ Q,
                                                   const u16* __restrict__ K,
                                                   const u16* __restrict__ VT,
                                                   float* __restrict__ ctxn, int N){
  constexpr int KP = C + 8;
  __shared__ u16 Ks[32*KP];
  __shared__ u16 Vt[C*40];
  __shared__ u16 ps[4][16*40];
  int t = threadIdx.x, wid = t>>6, lane = t&63;
  int l15 = lane&15, g = lane>>4;
  int p = blockIdx.y, j = blockIdx.z;
  int q0 = (blockIdx.x*4 + wid)*16;
  const u16* Qb = Q + ((size_t)(p+1)*N + q0)*C;
  const u16* Kb = K  + (size_t)(p + (j?2:0))*N*C;
  const u16* Vb = VT + (size_t)(p + (j?2:0))*C*N;

  short8v qf[C/32];
  #pragma unroll
  for(int kk = 0; kk < C/32; kk++)
    qf[kk] = *(const short8v*)(Qb + (size_t)l15*C + kk*32 + 8*g);

  f32x4 acc[C/16];
  #pragma unroll
  for(int i = 0; i < C/16; i++) acc[i] = f32x4{0.f,0.f,0.f,0.f};
  float mrow[4] = {-1e30f,-1e30f,-1e30f,-1e30f};
  float lrow[4] = {0.f,0.f,0.f,0.f};

  for(int m0 = 0; m0 < N; m0 += 32){
    __syncthreads();
    for(int idx = t*8; idx < 32*C; idx += 2048){
      int m = idx/C, c = idx - m*C;
      *(short8v*)(Ks + m*KP + c) = *(const short8v*)(Kb + (size_t)(m0+m)*C + c);
    }
    for(int idx = t*8; idx < 32*C; idx += 2048){
      int c = idx >> 5, mo = idx & 31;
      *(short8v*)(Vt + c*40 + mo) = *(const short8v*)(Vb + (size_t)c*N + m0 + mo);
    }
    __syncthreads();
    f32x4 s0 = {0.f,0.f,0.f,0.f}, s1 = {0.f,0.f,0.f,0.f};
    #pragma unroll
    for(int kk = 0; kk < C/32; kk++){
      short8v k0 = *(const short8v*)(Ks + l15*KP      + kk*32 + 8*g);
      short8v k1 = *(const short8v*)(Ks + (16+l15)*KP + kk*32 + 8*g);
      s0 = __builtin_amdgcn_mfma_f32_16x16x32_bf16(qf[kk], k0, s0, 0,0,0);
      s1 = __builtin_amdgcn_mfma_f32_16x16x32_bf16(qf[kk], k1, s1, 0,0,0);
    }
    float scl[4];
    #pragma unroll
    for(int r = 0; r < 4; r++){
      float mx = fmaxf(s0[r], s1[r]);
      #pragma unroll
      for(int off = 1; off < 16; off <<= 1) mx = fmaxf(mx, __shfl_xor(mx, off));
      float mnew = fmaxf(mrow[r], mx);
      scl[r] = __expf(mrow[r] - mnew);
      float e0 = __expf(s0[r] - mnew), e1 = __expf(s1[r] - mnew);
      float psum = e0 + e1;
      #pragma unroll
      for(int off = 1; off < 16; off <<= 1) psum += __shfl_xor(psum, off);
      lrow[r] = lrow[r]*scl[r] + psum;
      mrow[r] = mnew;
      int m = 4*g + r;
      ps[wid][m*40 + l15]      = f2b(e0);
      ps[wid][m*40 + 16 + l15] = f2b(e1);
    }
    #pragma unroll
    for(int ct = 0; ct < C/16; ct++){
      #pragma unroll
      for(int r = 0; r < 4; r++) acc[ct][r] *= scl[r];
    }
    short8v pa = *(const short8v*)(ps[wid] + l15*40 + 8*g);
    #pragma unroll
    for(int ct = 0; ct < C/16; ct++){
      short8v vb = *(const short8v*)(Vt + (ct*16+l15)*40 + 8*g);
      acc[ct] = __builtin_amdgcn_mfma_f32_16x16x32_bf16(pa, vb, acc[ct], 0,0,0);
    }
  }
  #pragma unroll
  for(int ct = 0; ct < C/16; ct++){
    int c = ct*16 + l15;
    #pragma unroll
    for(int r = 0; r < 4; r++){
      int m = 4*g + r;
      atomicAdd(&ctxn[((size_t)p*N + q0 + m)*C + c], 0.5f*acc[ct][r]/lrow[r]);
    }
  }
}

// ---------- LayerNorm over C, wave-only ----------
__global__ __launch_bounds__(64) void k_ln64(float* __restrict__ ctxn, fp lng, fp lnb, int C){
  float* row = ctxn + (size_t)blockIdx.x*C;
  int t = threadIdx.x;
  float s = 0.f, s2 = 0.f;
  for(int c = t; c < C; c += 64){ float v = row[c]; s += v; s2 += v*v; }
  #pragma unroll
  for(int off = 32; off > 0; off >>= 1){ s += __shfl_xor(s, off); s2 += __shfl_xor(s2, off); }
  float m = s/(float)C, var = s2/(float)C - m*m;
  float ri = rsqrtf(var + 1e-5f);
  for(int c = t; c < C; c += 64) row[c] = (row[c] - m)*ri*lng[c] + lnb[c];
}

// ---------- cm[n][c] = mean_p ctxn[p][n][c] ----------
__global__ void k_cm(const float* __restrict__ ctxn, float* __restrict__ cm, int C, int N){
  int n = blockIdx.x;
  for(int c = threadIdx.x; c < C; c += blockDim.x){
    float s = 0.25f*( ctxn[((size_t)0*N + n)*C + c] + ctxn[((size_t)1*N + n)*C + c]
                    + ctxn[((size_t)2*N + n)*C + c] + ctxn[((size_t)3*N + n)*C + c]);
    cm[(size_t)n*C + c] = s;
  }
}

// ---------- h[b][c][n] += cm[n][c], fused per-channel stat accumulation ----------
__global__ __launch_bounds__(256) void k_addstat(float* __restrict__ h, const float* __restrict__ cm,
                                                 float* __restrict__ ss2, int C, int N){
  int bc = blockIdx.x; int c = bc % C;
  float* hp = h + (size_t)bc*N;
  float s = 0.f, s2 = 0.f;
  for(int n = threadIdx.x; n < N; n += blockDim.x){
    float v = hp[n] + cm[(size_t)n*C + c];
    hp[n] = v; s += v; s2 += v*v;
  }
  #pragma unroll
  for(int o = 32; o > 0; o >>= 1){ s += __shfl_down(s, o); s2 += __shfl_down(s2, o); }
  if((threadIdx.x & 63) == 0){
    atomicAdd(&ss2[c], s); atomicAdd(&ss2[C + c], s2);
  }
}
// ---------- finish BN scale/shift from raw sums ----------
__global__ void k_bnfin(const float* __restrict__ ss2, fp bng, fp bnb,
                        float* __restrict__ ss, int C, int N){
  int c = threadIdx.x;
  if(c >= C) return;
  float inv = 1.f/(6.f*(float)N);
  float m = ss2[c]*inv, var = ss2[C+c]*inv - m*m;
  float sc = bng[c]*rsqrtf(var + 1e-5f);
  ss[c] = sc; ss[C + c] = bnb[c] - m*sc;
}

// ---------- BN apply + ReLU, in place; also emit bf16 copy ----------
__global__ __launch_bounds__(256) void k_bnrelu2(float* __restrict__ h, const float* __restrict__ ssin,
                                                 u16* __restrict__ ob, int C, int N){
  int bc = blockIdx.x; int c = bc % C;
  float sc = ssin[c], sh = ssin[C + c];
  float* hp = h + (size_t)bc*N;
  u16* op = ob + (size_t)bc*N;
  for(int n = threadIdx.x; n < N; n += blockDim.x){
    float v = hp[n]*sc + sh; v = v > 0.f ? v : 0.f;
    hp[n] = v; op[n] = f2b(v);
  }
}

// ---------- final up2 + f32 store ----------
__global__ __launch_bounds__(256) void k_up_out(const float* __restrict__ in, float* out,
                                                int H, int W){
  int bc = blockIdx.x;
  const float* ip = in + (size_t)bc*H*W;
  float* op = out + (size_t)bc*4*H*W;
  int W2 = 2*W, N2 = 4*H*W;
  for(int p = threadIdx.x; p < N2; p += blockDim.x){
    int y = p / W2, x = p % W2;
    op[p] = ip[(y>>1)*W + (x>>1)];
  }
}

extern "C" void kernel_launch(void* const* d_in, const int* in_sizes, int n_in,
                              void* d_out, int out_size, void* d_ws, size_t ws_size,
                              hipStream_t stream){
  float* out_f = (float*)d_out;
  static const int EXP[36] = {294912,393216,786432,1572864,3538944,512,
    131072,256,262144,262144,262144,512,512,512,512,1179648,
    32768,128,65536,65536,65536,256,256,256,256,294912,
    8192,64,16384,16384,16384,128,128,128,128,73728};
  bool ok = (n_in == 36) && (out_size == 6291456);
  if(ok) for(int i = 0; i < 36; i++) if(in_sizes[i] != EXP[i]){ ok = false; break; }
  if(!ok){
    k_fill<<<(out_size+255)/256, 256, 0, stream>>>(out_f, out_size, 10.0f);
    return;
  }
  const size_t R = 3145728;
  const size_t NEED = (5*R + 4096)*sizeof(float);
  if(ws_size < NEED){
    k_fill<<<(out_size+255)/256, 256, 0, stream>>>(out_f, out_size, 100.0f);
    return;
  }
  (void)hipGetLastError();
  #define CKERR(code) do{ if(hipGetLastError() != hipSuccess){ \
      k_fill<<<(out_size+255)/256, 256, 0, stream>>>(out_f, out_size, (float)(code)); \
      return; } }while(0)

  fp x = (fp)d_in[0];
  fp skip[3]  = {(fp)d_in[1],(fp)d_in[2],(fp)d_in[3]};
  fp w_sc = (fp)d_in[4], b_sc = (fp)d_in[5];
  fp w_up[3] = {(fp)d_in[6], (fp)d_in[16],(fp)d_in[26]};
  fp b_up[3] = {(fp)d_in[7], (fp)d_in[17],(fp)d_in[27]};
  fp wq[3]   = {(fp)d_in[8], (fp)d_in[18],(fp)d_in[28]};
  fp wk[3]   = {(fp)d_in[9], (fp)d_in[19],(fp)d_in[29]};
  fp wv[3]   = {(fp)d_in[10],(fp)d_in[20],(fp)d_in[30]};
  fp lng[3]  = {(fp)d_in[11],(fp)d_in[21],(fp)d_in[31]};
  fp lnb[3]  = {(fp)d_in[12],(fp)d_in[22],(fp)d_in[32]};
  fp bng[3]  = {(fp)d_in[13],(fp)d_in[23],(fp)d_in[33]};
  fp bnb[3]  = {(fp)d_in[14],(fp)d_in[24],(fp)d_in[34]};
  fp w_cb[3] = {(fp)d_in[15],(fp)d_in[25],(fp)d_in[35]};

  float* Wp = (float*)d_ws;
  float *Cc = Wp, *CT = Wp + R;
  u16 *QB = (u16*)(Wp + 2*R), *KB = (u16*)(Wp + 3*R), *VB = (u16*)(Wp + 4*R);
  float *SS  = Wp + 5*R;          // finals: 2C
  float *SS2 = Wp + 5*R + 2048;   // raw sums: 2C
  float *OB = Wp + R, *Bf = Wp + 2*R, *CM = Wp + 2*R;   // aliases (liveness-verified)
  u16 *XB  = QB + R;
  u16 *WQT = KB + R;
  u16 *WT = KB, *IB = VB;

  // stage 0
  k_in_tr<<<dim3(64,6),256,0,stream>>>(x, Cc);
  k_b16<<<(294912/8+255)/256, 256, 0, stream>>>(Cc, IB, 294912);
  k_wtr<<<(9*512*768+255)/256, 256, 0, stream>>>(w_sc, WT, 512, 768);
  k_fillb<<<(6*512*64+255)/256, 256, 0, stream>>>(OB, b_sc, 512, 64);
  k_conv3_mfma2<<<dim3(1,8,6*8), 256, 0, stream>>>(WT, IB, OB, 768, 512, 8, 8, 8);
  CKERR(20);

  const int Cskip[3] = {256,128,64};
  const int Hs[3]    = {16,32,64};
  const int SPL[3]   = {4,2,1};
  int Cprev = 512;
  for(int i = 0; i < 3; i++){
    int H = Hs[i], N = H*H;
    int N1 = N/4;
    int Cup = Cprev/2;
    int C = Cup + Cskip[i];
    k_conv1_low<<<6*Cup, (N1<256?N1:256), Cprev*4, stream>>>(OB, w_up[i], b_up[i], Bf, Cprev, Cup, N1);
    k_concat_up<<<6*C, 256, 0, stream>>>(Bf, skip[i], Cc, Cup, Cskip[i], N, H);
    k_trb<<<dim3(N/32, C/32, 6), 256, 0, stream>>>(Cc, XB, C, N);
    float rsv = 1.f/sqrtf((float)C);
    k_wqkvt<<<(3*C*C+255)/256, 256, 0, stream>>>(wq[i], wk[i], wv[i], WQT, C, rsv);
    k_gemm_qkv<<<dim3(6*N/64, 3*C/64), 256, 0, stream>>>(XB, WQT, QB, KB, VB, C, N);
    CKERR(30 + 10*i);
    k_fill<<<(4*N*C+255)/256, 256, 0, stream>>>(CT, 4*N*C, 0.f);
    if(i==0) k_attn_mfma<512><<<dim3(N/64,4,2),256,0,stream>>>(QB,KB,VB,CT,N);
    if(i==1) k_attn_mfma<256><<<dim3(N/64,4,2),256,0,stream>>>(QB,KB,VB,CT,N);
    if(i==2) k_attn128<<<dim3(N/64,4,2),256,0,stream>>>(QB,KB,VB,CT,N);
    k_ln64<<<4*N, 64, 0, stream>>>(CT, lng[i], lnb[i], C);
    CKERR(32 + 10*i);
    k_cm<<<N, C, 0, stream>>>(CT, CM, C, N);
    k_fill<<<(2*C+255)/256, 256, 0, stream>>>(SS2, 2*C, 0.f);
    k_addstat<<<6*C, 256, 0, stream>>>(Cc, CM, SS2, C, N);
    k_bnfin<<<1, C, 0, stream>>>(SS2, bng[i], bnb[i], SS, C, N);
    k_bnrelu2<<<6*C, 256, 0, stream>>>(Cc, SS, IB, C, N);
    int Co = C/2, S = SPL[i];
    k_wtr<<<(9*Co*C+255)/256, 256, 0, stream>>>(w_cb[i], WT, Co, C);
    if(S > 1) k_fill<<<(6*Co*N+255)/256, 256, 0, stream>>>(OB, 6*Co*N, 0.f);
    k_conv3_mfma2<<<dim3(N/64, Co/64, 6*S), 256, 0, stream>>>(WT, IB, OB, C, Co, H, H, S);
    CKERR(34 + 10*i);
    Cprev = Co;
  }
  k_up_out<<<6*64, 256, 0, stream>>>(OB, out_f, 64, 64);
  CKERR(90);
  #undef CKERR
}